// Round 2
// baseline (509.353 us; speedup 1.0000x reference)
//
#include <hip/hip_runtime.h>

#define DD 160
#define HH 160
#define WW 160
#define PL (HH*WW)       // one z-plane = 25600 voxels
#define S (DD*PL)        // 4,096,000 voxels

__device__ __forceinline__ float fmul(float a, float b){ return __fmul_rn(a,b); }
__device__ __forceinline__ float fadd(float a, float b){ return __fadd_rn(a,b); }
__device__ __forceinline__ float fsub(float a, float b){ return __fsub_rn(a,b); }

// Split intermediate layout: (d,h) interleaved float2 at buf[0..2S), w planar at
// buf[2S..3S).  Per gather tap: one 8B-aligned dwordx2 + one dword (12 line-touches
// /tap/wave vs 36 for 12B-interleaved) — attacks the TCP line-throughput bound.

// ddf0 = (dvf0*(1-w) + dvf1*w) / 32, planar in -> split out
__global__ __launch_bounds__(256) void init_kernel(const float* __restrict__ dvf0,
                                                   const float* __restrict__ dvf1,
                                                   const float* __restrict__ wp,
                                                   float* __restrict__ outb) {
    int p = (blockIdx.x * 256 + threadIdx.x) * 4;   // 4000 blocks cover S exactly
    float w = wp[0];
    float onew = fsub(1.0f, w);
    float a0[4], a1[4], a2[4], b0[4], b1[4], b2[4];
    *(float4*)a0 = *(const float4*)(dvf0 + p);
    *(float4*)a1 = *(const float4*)(dvf0 + S + p);
    *(float4*)a2 = *(const float4*)(dvf0 + 2 * S + p);
    *(float4*)b0 = *(const float4*)(dvf1 + p);
    *(float4*)b1 = *(const float4*)(dvf1 + S + p);
    *(float4*)b2 = *(const float4*)(dvf1 + 2 * S + p);
    float odh[8], ow[4];
    #pragma unroll
    for (int j = 0; j < 4; ++j) {
        odh[2*j]   = fmul(fadd(fmul(a0[j], onew), fmul(b0[j], w)), 0.03125f);  // d
        odh[2*j+1] = fmul(fadd(fmul(a1[j], onew), fmul(b1[j], w)), 0.03125f);  // h
        ow[j]      = fmul(fadd(fmul(a2[j], onew), fmul(b2[j], w)), 0.03125f);  // w
    }
    float* dstDH = outb + (size_t)2 * p;
    *(float4*)(dstDH)     = *(float4*)(odh);
    *(float4*)(dstDH + 4) = *(float4*)(odh + 4);
    *(float4*)(outb + (size_t)2 * S + p) = *(float4*)(ow);
}

// out = in + trilinear_warp(in, in).  Split input; uniform path (no fast/slow branch
// — round-1 showed VALU is not the bottleneck).  2 voxels/thread (z).
// Grid: 5(x) * 20(y) * 80(z-pairs) = 8000 blocks; swizzle -> 20-plane slab per XCD.
template<bool PLANAR>
__global__ __launch_bounds__(256) void warp_step(const float* __restrict__ in,
                                                 float* __restrict__ out) {
    const float* inDH = in;
    const float* inW  = in + (size_t)2 * S;
    int b  = (blockIdx.x & 7) * 1000 + (blockIdx.x >> 3);
    int ix = b % 5;
    int r  = b / 5;
    int iy = r % 20;
    int iz = r / 20;                 // 0..79
    int lane = threadIdx.x & 63, wid = threadIdx.x >> 6;
    int x  = (ix << 5) | (lane & 31);
    int y  = (iy << 3) | (wid << 1) | (lane >> 5);
    int z0 = iz << 1;
    int p0 = (z0 * HH + y) * WW + x;

    // center loads for both voxels: one dwordx2 + one dword each
    float cd_[2], ch_[2], cw_[2];
    #pragma unroll
    for (int j = 0; j < 2; ++j) {
        int pc = p0 + j * PL;
        float2 t = *(const float2*)(inDH + (size_t)2 * pc);
        cd_[j] = t.x; ch_[j] = t.y; cw_[j] = inW[pc];
    }

    #pragma unroll
    for (int j = 0; j < 2; ++j) {
        int z = z0 + j;
        int p = p0 + j * PL;
        float vd = cd_[j], vh = ch_[j], vw = cw_[j];
        float cd = fadd((float)z, vd);
        float ch = fadd((float)y, vh);
        float cw = fadd((float)x, vw);

        float d0 = floorf(cd), h0 = floorf(ch), w0 = floorf(cw);
        float fd = fsub(cd, d0), fh = fsub(ch, h0), fw = fsub(cw, w0);
        float gd = fsub(1.0f, fd), gh = fsub(1.0f, fh), gw = fsub(1.0f, fw);
        int d0i = (int)d0, h0i = (int)h0, w0i = (int)w0;

        // phase 1: addresses + weights for all 8 taps
        int   qa[8];
        float wt[8];
        #pragma unroll
        for (int t = 0; t < 8; ++t) {
            int dd = t >> 2, dh = (t >> 1) & 1, dw = t & 1;
            int di = d0i + dd, hi = h0i + dh, wi = w0i + dw;
            bool valid = (di >= 0) & (di < DD) & (hi >= 0) & (hi < HH)
                       & (wi >= 0) & (wi < WW);
            float wgt = fmul(fmul(dd ? fd : gd, dh ? fh : gh), dw ? fw : gw);
            wt[t] = valid ? wgt : 0.0f;     // 0*v == ref's v*0 (values finite)
            int dc = min(max(di, 0), DD - 1);
            int hc = min(max(hi, 0), HH - 1);
            int wc = min(max(wi, 0), WW - 1);
            qa[t] = (dc * HH + hc) * WW + wc;
        }
        // phase 2: issue all 8 tap loads (dwordx2 + dword each) -> 8-deep MLP
        float g0[8], g1[8], g2[8];
        #pragma unroll
        for (int t = 0; t < 8; ++t) {
            float2 t2 = *(const float2*)(inDH + (size_t)2 * qa[t]);
            g0[t] = t2.x; g1[t] = t2.y;
            g2[t] = inW[qa[t]];
        }
        // phase 3: accumulate in reference tap order
        float acc0 = 0.0f, acc1 = 0.0f, acc2 = 0.0f;
        #pragma unroll
        for (int t = 0; t < 8; ++t) {
            acc0 = fadd(acc0, fmul(g0[t], wt[t]));
            acc1 = fadd(acc1, fmul(g1[t], wt[t]));
            acc2 = fadd(acc2, fmul(g2[t], wt[t]));
        }
        float r0 = fadd(vd, acc0);
        float r1 = fadd(vh, acc1);
        float r2 = fadd(vw, acc2);

        if (PLANAR) {
            out[p] = r0; out[S + p] = r1; out[2 * S + p] = r2;
        } else {
            float2* dst = (float2*)(out + (size_t)2 * p);
            *dst = make_float2(r0, r1);
            out[(size_t)2 * S + p] = r2;
        }
    }
}

// img trilinear + cav/cor nearest warp with final (planar) ddf. 2 voxels/thread (z).
__global__ __launch_bounds__(256) void final_kernel(const float* __restrict__ ddf,
                                                    const float* __restrict__ image,
                                                    const int* __restrict__ cav,
                                                    const int* __restrict__ cor,
                                                    float* __restrict__ out) {
    int b  = (blockIdx.x & 7) * 1000 + (blockIdx.x >> 3);
    int ix = b % 5;
    int r  = b / 5;
    int iy = r % 20;
    int iz = r / 20;                 // 0..79
    int lane = threadIdx.x & 63, wid = threadIdx.x >> 6;
    int x  = (ix << 5) | (lane & 31);
    int y  = (iy << 3) | (wid << 1) | (lane >> 5);
    int z0 = iz << 1;
    int p0 = (z0 * HH + y) * WW + x;

    float dzs[2], dhs[2], dws[2];
    #pragma unroll
    for (int j = 0; j < 2; ++j) {
        dzs[j] = ddf[p0 + j * PL];
        dhs[j] = ddf[S + p0 + j * PL];
        dws[j] = ddf[2 * S + p0 + j * PL];
    }

    #pragma unroll
    for (int j = 0; j < 2; ++j) {
        int z = z0 + j;
        int p = p0 + j * PL;
        float cd = fadd((float)z, dzs[j]);
        float ch = fadd((float)y, dhs[j]);
        float cw = fadd((float)x, dws[j]);

        float d0 = floorf(cd), h0 = floorf(ch), w0 = floorf(cw);
        float fd = fsub(cd, d0), fh = fsub(ch, h0), fw = fsub(cw, w0);
        float gd = fsub(1.0f, fd), gh = fsub(1.0f, fh), gw = fsub(1.0f, fw);
        int d0i = (int)d0, h0i = (int)h0, w0i = (int)w0;

        bool fast = ((unsigned)d0i < (unsigned)(DD - 1))
                  & ((unsigned)h0i < (unsigned)(HH - 1))
                  & ((unsigned)w0i < (unsigned)(WW - 1));
        if (fast) {
            // planar image: base + immediate offsets {0,4,640,644}B
            const float* bp0 = image + (d0i * HH + h0i) * WW + w0i;
            const float* bp1 = bp0 + PL;
            float g[8];
            g[0] = bp0[0];      g[1] = bp0[1];
            g[2] = bp0[WW];     g[3] = bp0[WW + 1];
            g[4] = bp1[0];      g[5] = bp1[1];
            g[6] = bp1[WW];     g[7] = bp1[WW + 1];
            float w00 = fmul(gd, gh), w01 = fmul(gd, fh);
            float w10 = fmul(fd, gh), w11 = fmul(fd, fh);
            float wt[8] = { fmul(w00, gw), fmul(w00, fw), fmul(w01, gw), fmul(w01, fw),
                            fmul(w10, gw), fmul(w10, fw), fmul(w11, gw), fmul(w11, fw) };
            float acc = 0.0f;
            #pragma unroll
            for (int t = 0; t < 8; ++t) acc = fadd(acc, fmul(g[t], wt[t]));
            out[p] = acc;

            // nearest tap: rint(c) in [d0i, d0i+1] subset [0,159] -> always valid
            int di = (int)rintf(cd), hi = (int)rintf(ch), wi = (int)rintf(cw);
            int q = (di * HH + hi) * WW + wi;
            out[S + p]     = (float)cav[q];
            out[2 * S + p] = (float)cor[q];
        } else {
            int   qa[8];
            float wt[8];
            #pragma unroll
            for (int t = 0; t < 8; ++t) {
                int dd = t >> 2, dh = (t >> 1) & 1, dw = t & 1;
                int di = d0i + dd, hi = h0i + dh, wi = w0i + dw;
                bool valid = (di >= 0) & (di < DD) & (hi >= 0) & (hi < HH)
                           & (wi >= 0) & (wi < WW);
                float wgt = fmul(fmul(dd ? fd : gd, dh ? fh : gh), dw ? fw : gw);
                wt[t] = valid ? wgt : 0.0f;
                int dc = min(max(di, 0), DD - 1);
                int hc = min(max(hi, 0), HH - 1);
                int wc = min(max(wi, 0), WW - 1);
                qa[t] = (dc * HH + hc) * WW + wc;
            }
            float g[8];
            #pragma unroll
            for (int t = 0; t < 8; ++t) g[t] = image[qa[t]];
            float acc = 0.0f;
            #pragma unroll
            for (int t = 0; t < 8; ++t) acc = fadd(acc, fmul(g[t], wt[t]));
            out[p] = acc;

            // nearest labels (round half to even, matches jnp.round)
            int di = (int)rintf(cd), hi = (int)rintf(ch), wi = (int)rintf(cw);
            bool valid = (di >= 0) & (di < DD) & (hi >= 0) & (hi < HH)
                       & (wi >= 0) & (wi < WW);
            int dc = min(max(di, 0), DD - 1);
            int hc = min(max(hi, 0), HH - 1);
            int wc = min(max(wi, 0), WW - 1);
            int q = (dc * HH + hc) * WW + wc;
            out[S + p]     = valid ? (float)cav[q] : 0.0f;
            out[2 * S + p] = valid ? (float)cor[q] : 0.0f;
        }
    }
}

extern "C" void kernel_launch(void* const* d_in, const int* in_sizes, int n_in,
                              void* d_out, int out_size, void* d_ws, size_t ws_size,
                              hipStream_t stream) {
    const float* dvf0   = (const float*)d_in[0];
    const float* dvf1   = (const float*)d_in[1];
    const float* image  = (const float*)d_in[2];
    const int*   cav    = (const int*)d_in[3];
    const int*   cor    = (const int*)d_in[4];
    const float* w      = (const float*)d_in[5];

    float* out  = (float*)d_out;
    float* bufA = out;                    // split scratch; img/cav/cor at the end
    float* bufB = out + (size_t)3 * S;    // split scratch; final planar ddf

    init_kernel<<<4000, 256, 0, stream>>>(dvf0, dvf1, w, bufA);
    warp_step<false><<<8000, 256, 0, stream>>>(bufA, bufB);   // s1
    warp_step<false><<<8000, 256, 0, stream>>>(bufB, bufA);   // s2
    warp_step<false><<<8000, 256, 0, stream>>>(bufA, bufB);   // s3
    warp_step<false><<<8000, 256, 0, stream>>>(bufB, bufA);   // s4
    warp_step<true ><<<8000, 256, 0, stream>>>(bufA, bufB);   // s5 -> planar ddf in bufB
    final_kernel<<<8000, 256, 0, stream>>>(bufB, image, cav, cor, bufA);
}

// Round 3
// 440.428 us; speedup vs baseline: 1.1565x; 1.1565x over previous
//
#include <hip/hip_runtime.h>

#define DD 160
#define HH 160
#define WW 160
#define PL (HH*WW)       // one z-plane = 25600 voxels
#define S (DD*PL)        // 4,096,000 voxels

__device__ __forceinline__ float fmul(float a, float b){ return __fmul_rn(a,b); }
__device__ __forceinline__ float fadd(float a, float b){ return __fadd_rn(a,b); }
__device__ __forceinline__ float fsub(float a, float b){ return __fsub_rn(a,b); }

// ---------------------------------------------------------------------------
// Intermediates are PLANAR (d,h,w channels at +0, +S, +2S).
// warp_step stages each block's tap region into LDS (coalesced TCP reads) and
// gathers from LDS: moves the 24-lane-dword/voxel divergent gather off the
// TCP pipe (~4 addr/cyc divergent) onto the DS pipe (~11 lanes/cyc, stride-1
// conflict-free here).  Halo per step from |ddf_k| <= 2^k * max|dvf|/32:
// steps 1-3: H=1, step 4: H=2, step 5: H=3.  Out-of-halo voxels (possible
// only if the analytic bound is violated) take the exact global slow path.
// ---------------------------------------------------------------------------

// ddf0 = (dvf0*(1-w) + dvf1*w) / 32, planar in -> planar out
__global__ __launch_bounds__(256) void init_kernel(const float* __restrict__ dvf0,
                                                   const float* __restrict__ dvf1,
                                                   const float* __restrict__ wp,
                                                   float* __restrict__ outb) {
    int p = (blockIdx.x * 256 + threadIdx.x) * 4;   // 4000 blocks cover S exactly
    float w = wp[0];
    float onew = fsub(1.0f, w);
    #pragma unroll
    for (int c = 0; c < 3; ++c) {
        float a[4], b[4], o[4];
        *(float4*)a = *(const float4*)(dvf0 + (size_t)c * S + p);
        *(float4*)b = *(const float4*)(dvf1 + (size_t)c * S + p);
        #pragma unroll
        for (int j = 0; j < 4; ++j)
            o[j] = fmul(fadd(fmul(a[j], onew), fmul(b[j], w)), 0.03125f);
        *(float4*)(outb + (size_t)c * S + p) = *(float4*)(o);
    }
}

// out = in + trilinear_warp(in, in); planar in/out; LDS-staged gather.
// Tile 32(x) x 8(y) x 4(z) per block; grid 5*20*40 = 4000 blocks.
template<int H>
__global__ __launch_bounds__(256) void warp_step(const float* __restrict__ in,
                                                 float* __restrict__ out) {
    constexpr int RX = 32 + 2 * H;
    constexpr int RY = 8 + 2 * H;
    constexpr int RZ = 4 + 2 * H;
    constexpr int CH = RX * RY * RZ;      // floats per channel
    __shared__ float smem[3 * CH];

    int b  = (blockIdx.x & 7) * 500 + (blockIdx.x >> 3);   // XCD swizzle
    int ix = b % 5;
    int r  = b / 5;
    int iy = r % 20;
    int iz = r / 20;                 // 0..39
    int x0 = ix << 5, y0 = iy << 3, z0 = iz << 2;
    int xs = x0 - H, ys = y0 - H, zs = z0 - H;

    int tid = threadIdx.x;
    // ---- stage region (source clamped per-dim -> border slots duplicate edge)
    for (int s = tid; s < CH; s += 256) {
        int rz  = s / (RY * RX);
        int rem = s - rz * (RY * RX);
        int ry  = rem / RX;
        int rx  = rem - ry * RX;
        int cz = min(max(zs + rz, 0), DD - 1);
        int cy = min(max(ys + ry, 0), HH - 1);
        int cx = min(max(xs + rx, 0), WW - 1);
        int q = (cz * HH + cy) * WW + cx;
        smem[s]          = in[q];
        smem[CH + s]     = in[S + q];
        smem[2 * CH + s] = in[2 * S + q];
    }
    __syncthreads();

    int lane = tid & 63, wid = tid >> 6;
    int x = x0 | (lane & 31);
    int y = y0 | (wid << 1) | (lane >> 5);

    for (int j = 0; j < 4; ++j) {
        int z = z0 + j;
        int p = (z * HH + y) * WW + x;
        // center values from LDS (exact copies of in[p] etc.)
        int lc = ((j + H) * RY + (y - ys)) * RX + (x - xs);
        float vd = smem[lc], vh = smem[CH + lc], vw = smem[2 * CH + lc];

        float cd = fadd((float)z, vd);
        float ch = fadd((float)y, vh);
        float cw = fadd((float)x, vw);

        float d0 = floorf(cd), h0 = floorf(ch), w0 = floorf(cw);
        float fd = fsub(cd, d0), fh = fsub(ch, h0), fw = fsub(cw, w0);
        float gd = fsub(1.0f, fd), gh = fsub(1.0f, fh), gw = fsub(1.0f, fw);
        int d0i = (int)d0, h0i = (int)h0, w0i = (int)w0;

        int rd = d0i - zs, rh = h0i - ys, rw = w0i - xs;
        bool ok = ((unsigned)rd < (unsigned)(RZ - 1))
                & ((unsigned)rh < (unsigned)(RY - 1))
                & ((unsigned)rw < (unsigned)(RX - 1));

        float r0, r1, r2;
        if (ok) {
            // validity of taps vs the VOLUME (weights zeroed outside, as ref)
            bool vA0 = (d0i >= 0), vA1 = (d0i + 1 < DD);
            bool vB0 = (h0i >= 0), vB1 = (h0i + 1 < HH);
            bool vC0 = (w0i >= 0), vC1 = (w0i + 1 < WW);
            float wt[8];
            #pragma unroll
            for (int t = 0; t < 8; ++t) {
                int dd = t >> 2, dh = (t >> 1) & 1, dw = t & 1;
                bool valid = (dd ? vA1 : vA0) & (dh ? vB1 : vB0) & (dw ? vC1 : vC0);
                float wgt = fmul(fmul(dd ? fd : gd, dh ? fh : gh), dw ? fw : gw);
                wt[t] = valid ? wgt : 0.0f;
            }
            int l0 = (rd * RY + rh) * RX + rw;
            const int off[8] = { 0, 1, RX, RX + 1,
                                 RY * RX, RY * RX + 1, (RY + 1) * RX, (RY + 1) * RX + 1 };
            float acc0 = 0.0f, acc1 = 0.0f, acc2 = 0.0f;
            #pragma unroll
            for (int t = 0; t < 8; ++t) {
                int li = l0 + off[t];
                float ga = smem[li];
                float gb = smem[CH + li];
                float gc = smem[2 * CH + li];
                acc0 = fadd(acc0, fmul(ga, wt[t]));
                acc1 = fadd(acc1, fmul(gb, wt[t]));
                acc2 = fadd(acc2, fmul(gc, wt[t]));
            }
            r0 = fadd(vd, acc0);
            r1 = fadd(vh, acc1);
            r2 = fadd(vw, acc2);
        } else {
            // bound-violation fallback: exact global gather (clamped addrs)
            int   qa[8];
            float wt[8];
            #pragma unroll
            for (int t = 0; t < 8; ++t) {
                int dd = t >> 2, dh = (t >> 1) & 1, dw = t & 1;
                int di = d0i + dd, hi = h0i + dh, wi = w0i + dw;
                bool valid = (di >= 0) & (di < DD) & (hi >= 0) & (hi < HH)
                           & (wi >= 0) & (wi < WW);
                float wgt = fmul(fmul(dd ? fd : gd, dh ? fh : gh), dw ? fw : gw);
                wt[t] = valid ? wgt : 0.0f;
                int dc = min(max(di, 0), DD - 1);
                int hc = min(max(hi, 0), HH - 1);
                int wc = min(max(wi, 0), WW - 1);
                qa[t] = (dc * HH + hc) * WW + wc;
            }
            float acc0 = 0.0f, acc1 = 0.0f, acc2 = 0.0f;
            #pragma unroll
            for (int t = 0; t < 8; ++t) {
                acc0 = fadd(acc0, fmul(in[qa[t]], wt[t]));
                acc1 = fadd(acc1, fmul(in[S + qa[t]], wt[t]));
                acc2 = fadd(acc2, fmul(in[2 * S + qa[t]], wt[t]));
            }
            r0 = fadd(vd, acc0);
            r1 = fadd(vh, acc1);
            r2 = fadd(vw, acc2);
        }

        out[p] = r0; out[S + p] = r1; out[2 * S + p] = r2;
    }
}

// img trilinear + cav/cor nearest warp with final (planar) ddf. 2 voxels/thread (z).
__global__ __launch_bounds__(256) void final_kernel(const float* __restrict__ ddf,
                                                    const float* __restrict__ image,
                                                    const int* __restrict__ cav,
                                                    const int* __restrict__ cor,
                                                    float* __restrict__ out) {
    int b  = (blockIdx.x & 7) * 1000 + (blockIdx.x >> 3);
    int ix = b % 5;
    int r  = b / 5;
    int iy = r % 20;
    int iz = r / 20;                 // 0..79
    int lane = threadIdx.x & 63, wid = threadIdx.x >> 6;
    int x  = (ix << 5) | (lane & 31);
    int y  = (iy << 3) | (wid << 1) | (lane >> 5);
    int z0 = iz << 1;
    int p0 = (z0 * HH + y) * WW + x;

    float dzs[2], dhs[2], dws[2];
    #pragma unroll
    for (int j = 0; j < 2; ++j) {
        dzs[j] = ddf[p0 + j * PL];
        dhs[j] = ddf[S + p0 + j * PL];
        dws[j] = ddf[2 * S + p0 + j * PL];
    }

    #pragma unroll
    for (int j = 0; j < 2; ++j) {
        int z = z0 + j;
        int p = p0 + j * PL;
        float cd = fadd((float)z, dzs[j]);
        float ch = fadd((float)y, dhs[j]);
        float cw = fadd((float)x, dws[j]);

        float d0 = floorf(cd), h0 = floorf(ch), w0 = floorf(cw);
        float fd = fsub(cd, d0), fh = fsub(ch, h0), fw = fsub(cw, w0);
        float gd = fsub(1.0f, fd), gh = fsub(1.0f, fh), gw = fsub(1.0f, fw);
        int d0i = (int)d0, h0i = (int)h0, w0i = (int)w0;

        bool fast = ((unsigned)d0i < (unsigned)(DD - 1))
                  & ((unsigned)h0i < (unsigned)(HH - 1))
                  & ((unsigned)w0i < (unsigned)(WW - 1));
        if (fast) {
            const float* bp0 = image + (d0i * HH + h0i) * WW + w0i;
            const float* bp1 = bp0 + PL;
            float g[8];
            g[0] = bp0[0];      g[1] = bp0[1];
            g[2] = bp0[WW];     g[3] = bp0[WW + 1];
            g[4] = bp1[0];      g[5] = bp1[1];
            g[6] = bp1[WW];     g[7] = bp1[WW + 1];
            float w00 = fmul(gd, gh), w01 = fmul(gd, fh);
            float w10 = fmul(fd, gh), w11 = fmul(fd, fh);
            float wt[8] = { fmul(w00, gw), fmul(w00, fw), fmul(w01, gw), fmul(w01, fw),
                            fmul(w10, gw), fmul(w10, fw), fmul(w11, gw), fmul(w11, fw) };
            float acc = 0.0f;
            #pragma unroll
            for (int t = 0; t < 8; ++t) acc = fadd(acc, fmul(g[t], wt[t]));
            out[p] = acc;

            int di = (int)rintf(cd), hi = (int)rintf(ch), wi = (int)rintf(cw);
            int q = (di * HH + hi) * WW + wi;
            out[S + p]     = (float)cav[q];
            out[2 * S + p] = (float)cor[q];
        } else {
            int   qa[8];
            float wt[8];
            #pragma unroll
            for (int t = 0; t < 8; ++t) {
                int dd = t >> 2, dh = (t >> 1) & 1, dw = t & 1;
                int di = d0i + dd, hi = h0i + dh, wi = w0i + dw;
                bool valid = (di >= 0) & (di < DD) & (hi >= 0) & (hi < HH)
                           & (wi >= 0) & (wi < WW);
                float wgt = fmul(fmul(dd ? fd : gd, dh ? fh : gh), dw ? fw : gw);
                wt[t] = valid ? wgt : 0.0f;
                int dc = min(max(di, 0), DD - 1);
                int hc = min(max(hi, 0), HH - 1);
                int wc = min(max(wi, 0), WW - 1);
                qa[t] = (dc * HH + hc) * WW + wc;
            }
            float g[8];
            #pragma unroll
            for (int t = 0; t < 8; ++t) g[t] = image[qa[t]];
            float acc = 0.0f;
            #pragma unroll
            for (int t = 0; t < 8; ++t) acc = fadd(acc, fmul(g[t], wt[t]));
            out[p] = acc;

            int di = (int)rintf(cd), hi = (int)rintf(ch), wi = (int)rintf(cw);
            bool valid = (di >= 0) & (di < DD) & (hi >= 0) & (hi < HH)
                       & (wi >= 0) & (wi < WW);
            int dc = min(max(di, 0), DD - 1);
            int hc = min(max(hi, 0), HH - 1);
            int wc = min(max(wi, 0), WW - 1);
            int q = (dc * HH + hc) * WW + wc;
            out[S + p]     = valid ? (float)cav[q] : 0.0f;
            out[2 * S + p] = valid ? (float)cor[q] : 0.0f;
        }
    }
}

extern "C" void kernel_launch(void* const* d_in, const int* in_sizes, int n_in,
                              void* d_out, int out_size, void* d_ws, size_t ws_size,
                              hipStream_t stream) {
    const float* dvf0   = (const float*)d_in[0];
    const float* dvf1   = (const float*)d_in[1];
    const float* image  = (const float*)d_in[2];
    const int*   cav    = (const int*)d_in[3];
    const int*   cor    = (const int*)d_in[4];
    const float* w      = (const float*)d_in[5];

    float* out  = (float*)d_out;
    float* bufA = out;                    // planar scratch; img/cav/cor at the end
    float* bufB = out + (size_t)3 * S;    // planar scratch; final planar ddf

    init_kernel<<<4000, 256, 0, stream>>>(dvf0, dvf1, w, bufA);
    warp_step<1><<<4000, 256, 0, stream>>>(bufA, bufB);   // s1  |disp|<=0.18
    warp_step<1><<<4000, 256, 0, stream>>>(bufB, bufA);   // s2  |disp|<=0.36
    warp_step<1><<<4000, 256, 0, stream>>>(bufA, bufB);   // s3  |disp|<=0.72
    warp_step<2><<<4000, 256, 0, stream>>>(bufB, bufA);   // s4  |disp|<=1.43
    warp_step<3><<<4000, 256, 0, stream>>>(bufA, bufB);   // s5  |disp|<=2.86
    final_kernel<<<8000, 256, 0, stream>>>(bufB, image, cav, cor, bufA);
}

// Round 4
// 414.148 us; speedup vs baseline: 1.2299x; 1.0635x over previous
//
#include <hip/hip_runtime.h>

#define DD 160
#define HH 160
#define WW 160
#define PL (HH*WW)       // one z-plane = 25600 voxels
#define S (DD*PL)        // 4,096,000 voxels

__device__ __forceinline__ float fmul(float a, float b){ return __fmul_rn(a,b); }
__device__ __forceinline__ float fadd(float a, float b){ return __fadd_rn(a,b); }
__device__ __forceinline__ float fsub(float a, float b){ return __fsub_rn(a,b); }

// ---------------------------------------------------------------------------
// Pipeline (planar ddf intermediates):
//   fused_init_s1 : blend(dvf0,dvf1)/32 staged straight into LDS, + warp -> ddf1
//   warp_step<1>  : ddf2, ddf3        (LDS gather, halo 1, ratio 2.0)
//   warp_step<2>  : ddf4              (LDS gather, halo 2, ratio 3.4)
//   final_fused   : s5 flat gather (halo would be 3 -> LDS overfetch 5.2x loses
//                   to flat TCP gather) + image/label warp, one dispatch.
// ddf4 must live in a buffer distinct from both outputs -> d_ws (runtime-checked,
// race-free two-kernel fallback otherwise).
// ---------------------------------------------------------------------------

// out = in + trilinear_warp(in, in); planar in/out; LDS-staged gather.
// Tile 32(x) x 8(y) x 4(z) per block; grid 5*20*40 = 4000 blocks.
template<int H>
__global__ __launch_bounds__(256) void warp_step(const float* __restrict__ in,
                                                 float* __restrict__ out) {
    constexpr int RX = 32 + 2 * H;
    constexpr int RY = 8 + 2 * H;
    constexpr int RZ = 4 + 2 * H;
    constexpr int CH = RX * RY * RZ;      // floats per channel
    __shared__ float smem[3 * CH];

    int b  = (blockIdx.x & 7) * 500 + (blockIdx.x >> 3);   // XCD swizzle
    int ix = b % 5;
    int r  = b / 5;
    int iy = r % 20;
    int iz = r / 20;                 // 0..39
    int x0 = ix << 5, y0 = iy << 3, z0 = iz << 2;
    int xs = x0 - H, ys = y0 - H, zs = z0 - H;

    int tid = threadIdx.x;
    for (int s = tid; s < CH; s += 256) {
        int rz  = s / (RY * RX);
        int rem = s - rz * (RY * RX);
        int ry  = rem / RX;
        int rx  = rem - ry * RX;
        int cz = min(max(zs + rz, 0), DD - 1);
        int cy = min(max(ys + ry, 0), HH - 1);
        int cx = min(max(xs + rx, 0), WW - 1);
        int q = (cz * HH + cy) * WW + cx;
        smem[s]          = in[q];
        smem[CH + s]     = in[S + q];
        smem[2 * CH + s] = in[2 * S + q];
    }
    __syncthreads();

    int lane = tid & 63, wid = tid >> 6;
    int x = x0 | (lane & 31);
    int y = y0 | (wid << 1) | (lane >> 5);

    for (int j = 0; j < 4; ++j) {
        int z = z0 + j;
        int p = (z * HH + y) * WW + x;
        int lc = ((j + H) * RY + (y - ys)) * RX + (x - xs);
        float vd = smem[lc], vh = smem[CH + lc], vw = smem[2 * CH + lc];

        float cd = fadd((float)z, vd);
        float ch = fadd((float)y, vh);
        float cw = fadd((float)x, vw);

        float d0 = floorf(cd), h0 = floorf(ch), w0 = floorf(cw);
        float fd = fsub(cd, d0), fh = fsub(ch, h0), fw = fsub(cw, w0);
        float gd = fsub(1.0f, fd), gh = fsub(1.0f, fh), gw = fsub(1.0f, fw);
        int d0i = (int)d0, h0i = (int)h0, w0i = (int)w0;

        int rd = d0i - zs, rh = h0i - ys, rw = w0i - xs;
        bool ok = ((unsigned)rd < (unsigned)(RZ - 1))
                & ((unsigned)rh < (unsigned)(RY - 1))
                & ((unsigned)rw < (unsigned)(RX - 1));

        float r0, r1, r2;
        if (ok) {
            bool vA0 = (d0i >= 0), vA1 = (d0i + 1 < DD);
            bool vB0 = (h0i >= 0), vB1 = (h0i + 1 < HH);
            bool vC0 = (w0i >= 0), vC1 = (w0i + 1 < WW);
            float wt[8];
            #pragma unroll
            for (int t = 0; t < 8; ++t) {
                int dd = t >> 2, dh = (t >> 1) & 1, dw = t & 1;
                bool valid = (dd ? vA1 : vA0) & (dh ? vB1 : vB0) & (dw ? vC1 : vC0);
                float wgt = fmul(fmul(dd ? fd : gd, dh ? fh : gh), dw ? fw : gw);
                wt[t] = valid ? wgt : 0.0f;
            }
            int l0 = (rd * RY + rh) * RX + rw;
            const int off[8] = { 0, 1, RX, RX + 1,
                                 RY * RX, RY * RX + 1, (RY + 1) * RX, (RY + 1) * RX + 1 };
            float acc0 = 0.0f, acc1 = 0.0f, acc2 = 0.0f;
            #pragma unroll
            for (int t = 0; t < 8; ++t) {
                int li = l0 + off[t];
                acc0 = fadd(acc0, fmul(smem[li], wt[t]));
                acc1 = fadd(acc1, fmul(smem[CH + li], wt[t]));
                acc2 = fadd(acc2, fmul(smem[2 * CH + li], wt[t]));
            }
            r0 = fadd(vd, acc0);
            r1 = fadd(vh, acc1);
            r2 = fadd(vw, acc2);
        } else {
            int   qa[8];
            float wt[8];
            #pragma unroll
            for (int t = 0; t < 8; ++t) {
                int dd = t >> 2, dh = (t >> 1) & 1, dw = t & 1;
                int di = d0i + dd, hi = h0i + dh, wi = w0i + dw;
                bool valid = (di >= 0) & (di < DD) & (hi >= 0) & (hi < HH)
                           & (wi >= 0) & (wi < WW);
                float wgt = fmul(fmul(dd ? fd : gd, dh ? fh : gh), dw ? fw : gw);
                wt[t] = valid ? wgt : 0.0f;
                int dc = min(max(di, 0), DD - 1);
                int hc = min(max(hi, 0), HH - 1);
                int wc = min(max(wi, 0), WW - 1);
                qa[t] = (dc * HH + hc) * WW + wc;
            }
            float acc0 = 0.0f, acc1 = 0.0f, acc2 = 0.0f;
            #pragma unroll
            for (int t = 0; t < 8; ++t) {
                acc0 = fadd(acc0, fmul(in[qa[t]], wt[t]));
                acc1 = fadd(acc1, fmul(in[S + qa[t]], wt[t]));
                acc2 = fadd(acc2, fmul(in[2 * S + qa[t]], wt[t]));
            }
            r0 = fadd(vd, acc0);
            r1 = fadd(vh, acc1);
            r2 = fadd(vw, acc2);
        }

        out[p] = r0; out[S + p] = r1; out[2 * S + p] = r2;
    }
}

// init+s1 fused: stage blend((dvf0,dvf1),w)/32 into LDS directly; warp; -> ddf1.
__global__ __launch_bounds__(256) void fused_init_s1(const float* __restrict__ dvf0,
                                                     const float* __restrict__ dvf1,
                                                     const float* __restrict__ wp,
                                                     float* __restrict__ out) {
    constexpr int H = 1, RX = 34, RY = 10, RZ = 6, CH = RX * RY * RZ;
    __shared__ float smem[3 * CH];
    float w = wp[0];
    float onew = fsub(1.0f, w);

    int b  = (blockIdx.x & 7) * 500 + (blockIdx.x >> 3);
    int ix = b % 5;
    int r  = b / 5;
    int iy = r % 20;
    int iz = r / 20;
    int x0 = ix << 5, y0 = iy << 3, z0 = iz << 2;
    int xs = x0 - H, ys = y0 - H, zs = z0 - H;

    int tid = threadIdx.x;
    for (int s = tid; s < CH; s += 256) {
        int rz  = s / (RY * RX);
        int rem = s - rz * (RY * RX);
        int ry  = rem / RX;
        int rx  = rem - ry * RX;
        int cz = min(max(zs + rz, 0), DD - 1);
        int cy = min(max(ys + ry, 0), HH - 1);
        int cx = min(max(xs + rx, 0), WW - 1);
        int q = (cz * HH + cy) * WW + cx;
        #pragma unroll
        for (int c = 0; c < 3; ++c) {
            float a = dvf0[(size_t)c * S + q];
            float bb = dvf1[(size_t)c * S + q];
            smem[c * CH + s] = fmul(fadd(fmul(a, onew), fmul(bb, w)), 0.03125f);
        }
    }
    __syncthreads();

    int lane = tid & 63, wid = tid >> 6;
    int x = x0 | (lane & 31);
    int y = y0 | (wid << 1) | (lane >> 5);

    for (int j = 0; j < 4; ++j) {
        int z = z0 + j;
        int p = (z * HH + y) * WW + x;
        int lc = ((j + H) * RY + (y - ys)) * RX + (x - xs);
        float vd = smem[lc], vh = smem[CH + lc], vw = smem[2 * CH + lc];

        float cd = fadd((float)z, vd);
        float ch = fadd((float)y, vh);
        float cw = fadd((float)x, vw);

        float d0 = floorf(cd), h0 = floorf(ch), w0 = floorf(cw);
        float fd = fsub(cd, d0), fh = fsub(ch, h0), fw = fsub(cw, w0);
        float gd = fsub(1.0f, fd), gh = fsub(1.0f, fh), gw = fsub(1.0f, fw);
        int d0i = (int)d0, h0i = (int)h0, w0i = (int)w0;

        int rd = d0i - zs, rh = h0i - ys, rw = w0i - xs;
        bool ok = ((unsigned)rd < (unsigned)(RZ - 1))
                & ((unsigned)rh < (unsigned)(RY - 1))
                & ((unsigned)rw < (unsigned)(RX - 1));

        float r0, r1, r2;
        if (ok) {
            bool vA0 = (d0i >= 0), vA1 = (d0i + 1 < DD);
            bool vB0 = (h0i >= 0), vB1 = (h0i + 1 < HH);
            bool vC0 = (w0i >= 0), vC1 = (w0i + 1 < WW);
            float wt[8];
            #pragma unroll
            for (int t = 0; t < 8; ++t) {
                int dd = t >> 2, dh = (t >> 1) & 1, dw = t & 1;
                bool valid = (dd ? vA1 : vA0) & (dh ? vB1 : vB0) & (dw ? vC1 : vC0);
                float wgt = fmul(fmul(dd ? fd : gd, dh ? fh : gh), dw ? fw : gw);
                wt[t] = valid ? wgt : 0.0f;
            }
            int l0 = (rd * RY + rh) * RX + rw;
            const int off[8] = { 0, 1, RX, RX + 1,
                                 RY * RX, RY * RX + 1, (RY + 1) * RX, (RY + 1) * RX + 1 };
            float acc0 = 0.0f, acc1 = 0.0f, acc2 = 0.0f;
            #pragma unroll
            for (int t = 0; t < 8; ++t) {
                int li = l0 + off[t];
                acc0 = fadd(acc0, fmul(smem[li], wt[t]));
                acc1 = fadd(acc1, fmul(smem[CH + li], wt[t]));
                acc2 = fadd(acc2, fmul(smem[2 * CH + li], wt[t]));
            }
            r0 = fadd(vd, acc0);
            r1 = fadd(vh, acc1);
            r2 = fadd(vw, acc2);
        } else {
            // bound-violation fallback: recompute ddf0 at taps from dvf inputs
            int   qa[8];
            float wt[8];
            #pragma unroll
            for (int t = 0; t < 8; ++t) {
                int dd = t >> 2, dh = (t >> 1) & 1, dw = t & 1;
                int di = d0i + dd, hi = h0i + dh, wi = w0i + dw;
                bool valid = (di >= 0) & (di < DD) & (hi >= 0) & (hi < HH)
                           & (wi >= 0) & (wi < WW);
                float wgt = fmul(fmul(dd ? fd : gd, dh ? fh : gh), dw ? fw : gw);
                wt[t] = valid ? wgt : 0.0f;
                int dc = min(max(di, 0), DD - 1);
                int hc = min(max(hi, 0), HH - 1);
                int wc = min(max(wi, 0), WW - 1);
                qa[t] = (dc * HH + hc) * WW + wc;
            }
            float acc0 = 0.0f, acc1 = 0.0f, acc2 = 0.0f;
            #pragma unroll
            for (int t = 0; t < 8; ++t) {
                float ga = fmul(fadd(fmul(dvf0[qa[t]], onew), fmul(dvf1[qa[t]], w)), 0.03125f);
                float gb = fmul(fadd(fmul(dvf0[S + qa[t]], onew), fmul(dvf1[S + qa[t]], w)), 0.03125f);
                float gc = fmul(fadd(fmul(dvf0[2 * S + qa[t]], onew), fmul(dvf1[2 * S + qa[t]], w)), 0.03125f);
                acc0 = fadd(acc0, fmul(ga, wt[t]));
                acc1 = fadd(acc1, fmul(gb, wt[t]));
                acc2 = fadd(acc2, fmul(gc, wt[t]));
            }
            r0 = fadd(vd, acc0);
            r1 = fadd(vh, acc1);
            r2 = fadd(vw, acc2);
        }

        out[p] = r0; out[S + p] = r1; out[2 * S + p] = r2;
    }
}

// s5 (flat planar gather) computing ddf5 per voxel, then image/label warp.
// ddf4 (in) must be disjoint from both outputs.
__global__ __launch_bounds__(256) void final_fused(const float* __restrict__ ddf4,
                                                   const float* __restrict__ image,
                                                   const int* __restrict__ cav,
                                                   const int* __restrict__ cor,
                                                   float* __restrict__ outImg,
                                                   float* __restrict__ outDdf) {
    int b  = (blockIdx.x & 7) * 1000 + (blockIdx.x >> 3);
    int ix = b % 5;
    int r  = b / 5;
    int iy = r % 20;
    int iz = r / 20;                 // 0..79
    int lane = threadIdx.x & 63, wid = threadIdx.x >> 6;
    int x  = (ix << 5) | (lane & 31);
    int y  = (iy << 3) | (wid << 1) | (lane >> 5);
    int z0 = iz << 1;
    int p0 = (z0 * HH + y) * WW + x;

    #pragma unroll
    for (int j = 0; j < 2; ++j) {
        int z = z0 + j;
        int p = p0 + j * PL;

        // ---- s5: ddf5 = ddf4 + warp(ddf4, ddf4), flat gather
        float vd = ddf4[p], vh = ddf4[S + p], vw = ddf4[2 * S + p];
        float cd = fadd((float)z, vd);
        float ch = fadd((float)y, vh);
        float cw = fadd((float)x, vw);

        float d0 = floorf(cd), h0 = floorf(ch), w0 = floorf(cw);
        float fd = fsub(cd, d0), fh = fsub(ch, h0), fw = fsub(cw, w0);
        float gd = fsub(1.0f, fd), gh = fsub(1.0f, fh), gw = fsub(1.0f, fw);
        int d0i = (int)d0, h0i = (int)h0, w0i = (int)w0;

        int   qa[8];
        float wt[8];
        #pragma unroll
        for (int t = 0; t < 8; ++t) {
            int dd = t >> 2, dh = (t >> 1) & 1, dw = t & 1;
            int di = d0i + dd, hi = h0i + dh, wi = w0i + dw;
            bool valid = (di >= 0) & (di < DD) & (hi >= 0) & (hi < HH)
                       & (wi >= 0) & (wi < WW);
            float wgt = fmul(fmul(dd ? fd : gd, dh ? fh : gh), dw ? fw : gw);
            wt[t] = valid ? wgt : 0.0f;
            int dc = min(max(di, 0), DD - 1);
            int hc = min(max(hi, 0), HH - 1);
            int wc = min(max(wi, 0), WW - 1);
            qa[t] = (dc * HH + hc) * WW + wc;
        }
        float acc0 = 0.0f, acc1 = 0.0f, acc2 = 0.0f;
        #pragma unroll
        for (int t = 0; t < 8; ++t) {
            acc0 = fadd(acc0, fmul(ddf4[qa[t]], wt[t]));
            acc1 = fadd(acc1, fmul(ddf4[S + qa[t]], wt[t]));
            acc2 = fadd(acc2, fmul(ddf4[2 * S + qa[t]], wt[t]));
        }
        float r0 = fadd(vd, acc0);
        float r1 = fadd(vh, acc1);
        float r2 = fadd(vw, acc2);
        outDdf[p] = r0; outDdf[S + p] = r1; outDdf[2 * S + p] = r2;

        // ---- final: warp image (trilinear) + labels (nearest) with ddf5
        float cd2 = fadd((float)z, r0);
        float ch2 = fadd((float)y, r1);
        float cw2 = fadd((float)x, r2);

        float d02 = floorf(cd2), h02 = floorf(ch2), w02 = floorf(cw2);
        float fd2 = fsub(cd2, d02), fh2 = fsub(ch2, h02), fw2 = fsub(cw2, w02);
        float gd2 = fsub(1.0f, fd2), gh2 = fsub(1.0f, fh2), gw2 = fsub(1.0f, fw2);
        int d2i = (int)d02, h2i = (int)h02, w2i = (int)w02;

        bool fast = ((unsigned)d2i < (unsigned)(DD - 1))
                  & ((unsigned)h2i < (unsigned)(HH - 1))
                  & ((unsigned)w2i < (unsigned)(WW - 1));
        if (fast) {
            const float* bp0 = image + (d2i * HH + h2i) * WW + w2i;
            const float* bp1 = bp0 + PL;
            float g[8];
            g[0] = bp0[0];      g[1] = bp0[1];
            g[2] = bp0[WW];     g[3] = bp0[WW + 1];
            g[4] = bp1[0];      g[5] = bp1[1];
            g[6] = bp1[WW];     g[7] = bp1[WW + 1];
            float w00 = fmul(gd2, gh2), w01 = fmul(gd2, fh2);
            float w10 = fmul(fd2, gh2), w11 = fmul(fd2, fh2);
            float wtf[8] = { fmul(w00, gw2), fmul(w00, fw2), fmul(w01, gw2), fmul(w01, fw2),
                             fmul(w10, gw2), fmul(w10, fw2), fmul(w11, gw2), fmul(w11, fw2) };
            float acc = 0.0f;
            #pragma unroll
            for (int t = 0; t < 8; ++t) acc = fadd(acc, fmul(g[t], wtf[t]));
            outImg[p] = acc;

            int di = (int)rintf(cd2), hi = (int)rintf(ch2), wi = (int)rintf(cw2);
            int q = (di * HH + hi) * WW + wi;
            outImg[S + p]     = (float)cav[q];
            outImg[2 * S + p] = (float)cor[q];
        } else {
            int   qb[8];
            float wtf[8];
            #pragma unroll
            for (int t = 0; t < 8; ++t) {
                int dd = t >> 2, dh = (t >> 1) & 1, dw = t & 1;
                int di = d2i + dd, hi = h2i + dh, wi = w2i + dw;
                bool valid = (di >= 0) & (di < DD) & (hi >= 0) & (hi < HH)
                           & (wi >= 0) & (wi < WW);
                float wgt = fmul(fmul(dd ? fd2 : gd2, dh ? fh2 : gh2), dw ? fw2 : gw2);
                wtf[t] = valid ? wgt : 0.0f;
                int dc = min(max(di, 0), DD - 1);
                int hc = min(max(hi, 0), HH - 1);
                int wc = min(max(wi, 0), WW - 1);
                qb[t] = (dc * HH + hc) * WW + wc;
            }
            float acc = 0.0f;
            #pragma unroll
            for (int t = 0; t < 8; ++t) acc = fadd(acc, fmul(image[qb[t]], wtf[t]));
            outImg[p] = acc;

            int di = (int)rintf(cd2), hi = (int)rintf(ch2), wi = (int)rintf(cw2);
            bool valid = (di >= 0) & (di < DD) & (hi >= 0) & (hi < HH)
                       & (wi >= 0) & (wi < WW);
            int dc = min(max(di, 0), DD - 1);
            int hc = min(max(hi, 0), HH - 1);
            int wc = min(max(wi, 0), WW - 1);
            int q = (dc * HH + hc) * WW + wc;
            outImg[S + p]     = valid ? (float)cav[q] : 0.0f;
            outImg[2 * S + p] = valid ? (float)cor[q] : 0.0f;
        }
    }
}

// Fallback s5 (flat planar), used only if d_ws is too small.
__global__ __launch_bounds__(256) void warp_flat(const float* __restrict__ in,
                                                 float* __restrict__ out) {
    int b  = (blockIdx.x & 7) * 1000 + (blockIdx.x >> 3);
    int ix = b % 5;
    int r  = b / 5;
    int iy = r % 20;
    int iz = r / 20;
    int lane = threadIdx.x & 63, wid = threadIdx.x >> 6;
    int x  = (ix << 5) | (lane & 31);
    int y  = (iy << 3) | (wid << 1) | (lane >> 5);
    int z0 = iz << 1;
    int p0 = (z0 * HH + y) * WW + x;

    #pragma unroll
    for (int j = 0; j < 2; ++j) {
        int z = z0 + j;
        int p = p0 + j * PL;
        float vd = in[p], vh = in[S + p], vw = in[2 * S + p];
        float cd = fadd((float)z, vd);
        float ch = fadd((float)y, vh);
        float cw = fadd((float)x, vw);

        float d0 = floorf(cd), h0 = floorf(ch), w0 = floorf(cw);
        float fd = fsub(cd, d0), fh = fsub(ch, h0), fw = fsub(cw, w0);
        float gd = fsub(1.0f, fd), gh = fsub(1.0f, fh), gw = fsub(1.0f, fw);
        int d0i = (int)d0, h0i = (int)h0, w0i = (int)w0;

        int   qa[8];
        float wt[8];
        #pragma unroll
        for (int t = 0; t < 8; ++t) {
            int dd = t >> 2, dh = (t >> 1) & 1, dw = t & 1;
            int di = d0i + dd, hi = h0i + dh, wi = w0i + dw;
            bool valid = (di >= 0) & (di < DD) & (hi >= 0) & (hi < HH)
                       & (wi >= 0) & (wi < WW);
            float wgt = fmul(fmul(dd ? fd : gd, dh ? fh : gh), dw ? fw : gw);
            wt[t] = valid ? wgt : 0.0f;
            int dc = min(max(di, 0), DD - 1);
            int hc = min(max(hi, 0), HH - 1);
            int wc = min(max(wi, 0), WW - 1);
            qa[t] = (dc * HH + hc) * WW + wc;
        }
        float acc0 = 0.0f, acc1 = 0.0f, acc2 = 0.0f;
        #pragma unroll
        for (int t = 0; t < 8; ++t) {
            acc0 = fadd(acc0, fmul(in[qa[t]], wt[t]));
            acc1 = fadd(acc1, fmul(in[S + qa[t]], wt[t]));
            acc2 = fadd(acc2, fmul(in[2 * S + qa[t]], wt[t]));
        }
        out[p]         = fadd(vd, acc0);
        out[S + p]     = fadd(vh, acc1);
        out[2 * S + p] = fadd(vw, acc2);
    }
}

// Fallback final (reads ddf5 center-only; safe to write outImg == old ddf4 buffer).
__global__ __launch_bounds__(256) void final_kernel(const float* __restrict__ ddf,
                                                    const float* __restrict__ image,
                                                    const int* __restrict__ cav,
                                                    const int* __restrict__ cor,
                                                    float* __restrict__ out) {
    int b  = (blockIdx.x & 7) * 1000 + (blockIdx.x >> 3);
    int ix = b % 5;
    int r  = b / 5;
    int iy = r % 20;
    int iz = r / 20;
    int lane = threadIdx.x & 63, wid = threadIdx.x >> 6;
    int x  = (ix << 5) | (lane & 31);
    int y  = (iy << 3) | (wid << 1) | (lane >> 5);
    int z0 = iz << 1;
    int p0 = (z0 * HH + y) * WW + x;

    #pragma unroll
    for (int j = 0; j < 2; ++j) {
        int z = z0 + j;
        int p = p0 + j * PL;
        float cd = fadd((float)z, ddf[p]);
        float ch = fadd((float)y, ddf[S + p]);
        float cw = fadd((float)x, ddf[2 * S + p]);

        float d0 = floorf(cd), h0 = floorf(ch), w0 = floorf(cw);
        float fd = fsub(cd, d0), fh = fsub(ch, h0), fw = fsub(cw, w0);
        float gd = fsub(1.0f, fd), gh = fsub(1.0f, fh), gw = fsub(1.0f, fw);
        int d0i = (int)d0, h0i = (int)h0, w0i = (int)w0;

        int   qa[8];
        float wt[8];
        #pragma unroll
        for (int t = 0; t < 8; ++t) {
            int dd = t >> 2, dh = (t >> 1) & 1, dw = t & 1;
            int di = d0i + dd, hi = h0i + dh, wi = w0i + dw;
            bool valid = (di >= 0) & (di < DD) & (hi >= 0) & (hi < HH)
                       & (wi >= 0) & (wi < WW);
            float wgt = fmul(fmul(dd ? fd : gd, dh ? fh : gh), dw ? fw : gw);
            wt[t] = valid ? wgt : 0.0f;
            int dc = min(max(di, 0), DD - 1);
            int hc = min(max(hi, 0), HH - 1);
            int wc = min(max(wi, 0), WW - 1);
            qa[t] = (dc * HH + hc) * WW + wc;
        }
        float acc = 0.0f;
        #pragma unroll
        for (int t = 0; t < 8; ++t) acc = fadd(acc, fmul(image[qa[t]], wt[t]));
        out[p] = acc;

        int di = (int)rintf(cd), hi = (int)rintf(ch), wi = (int)rintf(cw);
        bool valid = (di >= 0) & (di < DD) & (hi >= 0) & (hi < HH)
                   & (wi >= 0) & (wi < WW);
        int dc = min(max(di, 0), DD - 1);
        int hc = min(max(hi, 0), HH - 1);
        int wc = min(max(wi, 0), WW - 1);
        int q = (dc * HH + hc) * WW + wc;
        out[S + p]     = valid ? (float)cav[q] : 0.0f;
        out[2 * S + p] = valid ? (float)cor[q] : 0.0f;
    }
}

extern "C" void kernel_launch(void* const* d_in, const int* in_sizes, int n_in,
                              void* d_out, int out_size, void* d_ws, size_t ws_size,
                              hipStream_t stream) {
    const float* dvf0   = (const float*)d_in[0];
    const float* dvf1   = (const float*)d_in[1];
    const float* image  = (const float*)d_in[2];
    const int*   cav    = (const int*)d_in[3];
    const int*   cor    = (const int*)d_in[4];
    const float* w      = (const float*)d_in[5];

    float* out  = (float*)d_out;
    float* bufA = out;                    // ends as img, cav, cor
    float* bufB = out + (size_t)3 * S;    // ends as ddf5 (planar)
    float* bufC = (float*)d_ws;           // ddf4 scratch (if big enough)
    bool useWs = (d_ws != nullptr) && (ws_size >= (size_t)3 * S * sizeof(float));

    fused_init_s1<<<4000, 256, 0, stream>>>(dvf0, dvf1, w, bufB);     // ddf1
    warp_step<1><<<4000, 256, 0, stream>>>(bufB, bufA);               // ddf2
    warp_step<1><<<4000, 256, 0, stream>>>(bufA, bufB);               // ddf3
    if (useWs) {
        warp_step<2><<<4000, 256, 0, stream>>>(bufB, bufC);           // ddf4 -> ws
        final_fused<<<8000, 256, 0, stream>>>(bufC, image, cav, cor, bufA, bufB);
    } else {
        warp_step<2><<<4000, 256, 0, stream>>>(bufB, bufA);           // ddf4
        warp_flat<<<8000, 256, 0, stream>>>(bufA, bufB);              // ddf5
        final_kernel<<<8000, 256, 0, stream>>>(bufB, image, cav, cor, bufA);
    }
}

// Round 5
// 376.814 us; speedup vs baseline: 1.3517x; 1.0991x over previous
//
#include <hip/hip_runtime.h>

#define DD 160
#define HH 160
#define WW 160
#define PL (HH*WW)       // one z-plane = 25600 voxels
#define S (DD*PL)        // 4,096,000 voxels

__device__ __forceinline__ float fmul(float a, float b){ return __fmul_rn(a,b); }
__device__ __forceinline__ float fadd(float a, float b){ return __fadd_rn(a,b); }
__device__ __forceinline__ float fsub(float a, float b){ return __fsub_rn(a,b); }

// ---------------------------------------------------------------------------
// All LDS tiles use 40-float (160B) rows spanning x in [x0-4, x0+36): 16B
// aligned -> float4 staging (4x fewer TCP slots).  x-halo slots outside the
// volume hold raw (unclamped) neighbors: only ever multiplied by exact +0.0
// weights, and all staged addresses clamped to [0, S-4] (written, finite).
// z/y are halo-exact and edge-clamped (correct values for valid taps).
//   fused_init_s1 : blend staged straight into LDS (H=1)      -> ddf1
//   warp_step<1>  : ddf2, ddf3   (28.8 KB, 5 blk/CU)
//   warp_step<2>  : ddf4         (46.1 KB, 3 blk/CU)
//   final_phased  : s5 via channel-phased H=3 LDS (22.4 KB/phase, 7 blk/CU)
//                   + image/label warp, one dispatch.
// ---------------------------------------------------------------------------

// out = in + trilinear_warp(in, in); planar in/out; LDS float4-staged gather.
// Tile 32(x) x 8(y) x 4(z); grid 5*20*40 = 4000 blocks, XCD-swizzled.
template<int H>
__global__ __launch_bounds__(256) void warp_step(const float* __restrict__ in,
                                                 float* __restrict__ out) {
    constexpr int RZ = 4 + 2 * H;
    constexpr int RY = 8 + 2 * H;
    constexpr int ROWS = RZ * RY;
    constexpr int NCH4 = ROWS * 10;       // float4 chunks per channel
    constexpr int CHF  = ROWS * 40;       // floats per channel
    __shared__ float smem[3 * CHF];

    int b  = (blockIdx.x & 7) * 500 + (blockIdx.x >> 3);
    int ix = b % 5;
    int r  = b / 5;
    int iy = r % 20;
    int iz = r / 20;                 // 0..39
    int x0 = ix << 5, y0 = iy << 3, z0 = iz << 2;
    int xs4 = x0 - 4, ys = y0 - H, zs = z0 - H;

    int tid = threadIdx.x;
    for (int c = tid; c < NCH4; c += 256) {
        int row = c / 10;
        int col = (c - row * 10) << 2;
        int rz  = row / RY;
        int ry  = row - rz * RY;
        int cz = min(max(zs + rz, 0), DD - 1);
        int cy = min(max(ys + ry, 0), HH - 1);
        int q  = min(max((cz * HH + cy) * WW + xs4 + col, 0), S - 4);
        float4 v0 = *(const float4*)(in + q);
        float4 v1 = *(const float4*)(in + S + q);
        float4 v2 = *(const float4*)(in + 2 * S + q);
        *(float4*)&smem[row * 40 + col]           = v0;
        *(float4*)&smem[CHF + row * 40 + col]     = v1;
        *(float4*)&smem[2 * CHF + row * 40 + col] = v2;
    }
    __syncthreads();

    int lane = tid & 63, wid = tid >> 6;
    int x = x0 | (lane & 31);
    int y = y0 | (wid << 1) | (lane >> 5);
    int lx = x - xs4;                 // 4..35
    int ly = y - ys;

    for (int j = 0; j < 4; ++j) {
        int z = z0 + j;
        int p = (z * HH + y) * WW + x;
        int lc = ((j + H) * RY + ly) * 40 + lx;
        float vd = smem[lc], vh = smem[CHF + lc], vw = smem[2 * CHF + lc];

        float cd = fadd((float)z, vd);
        float ch = fadd((float)y, vh);
        float cw = fadd((float)x, vw);

        float d0 = floorf(cd), h0 = floorf(ch), w0 = floorf(cw);
        float fd = fsub(cd, d0), fh = fsub(ch, h0), fw = fsub(cw, w0);
        float gd = fsub(1.0f, fd), gh = fsub(1.0f, fh), gw = fsub(1.0f, fw);
        int d0i = (int)d0, h0i = (int)h0, w0i = (int)w0;

        int rd = d0i - zs, rh = h0i - ys, rw = w0i - xs4;
        bool ok = ((unsigned)rd < (unsigned)(RZ - 1))
                & ((unsigned)rh < (unsigned)(RY - 1))
                & ((unsigned)rw < 39u);

        float r0, r1, r2;
        if (ok) {
            bool vA0 = (d0i >= 0), vA1 = (d0i + 1 < DD);
            bool vB0 = (h0i >= 0), vB1 = (h0i + 1 < HH);
            bool vC0 = (w0i >= 0), vC1 = (w0i + 1 < WW);
            float wt[8];
            #pragma unroll
            for (int t = 0; t < 8; ++t) {
                int dd = t >> 2, dh = (t >> 1) & 1, dw = t & 1;
                bool valid = (dd ? vA1 : vA0) & (dh ? vB1 : vB0) & (dw ? vC1 : vC0);
                float wgt = fmul(fmul(dd ? fd : gd, dh ? fh : gh), dw ? fw : gw);
                wt[t] = valid ? wgt : 0.0f;
            }
            int l0 = (rd * RY + rh) * 40 + rw;
            const int off[8] = { 0, 1, 40, 41,
                                 RY * 40, RY * 40 + 1, (RY + 1) * 40, (RY + 1) * 40 + 1 };
            float acc0 = 0.0f, acc1 = 0.0f, acc2 = 0.0f;
            #pragma unroll
            for (int t = 0; t < 8; ++t) {
                int li = l0 + off[t];
                acc0 = fadd(acc0, fmul(smem[li], wt[t]));
                acc1 = fadd(acc1, fmul(smem[CHF + li], wt[t]));
                acc2 = fadd(acc2, fmul(smem[2 * CHF + li], wt[t]));
            }
            r0 = fadd(vd, acc0);
            r1 = fadd(vh, acc1);
            r2 = fadd(vw, acc2);
        } else {
            int   qa[8];
            float wt[8];
            #pragma unroll
            for (int t = 0; t < 8; ++t) {
                int dd = t >> 2, dh = (t >> 1) & 1, dw = t & 1;
                int di = d0i + dd, hi = h0i + dh, wi = w0i + dw;
                bool valid = (di >= 0) & (di < DD) & (hi >= 0) & (hi < HH)
                           & (wi >= 0) & (wi < WW);
                float wgt = fmul(fmul(dd ? fd : gd, dh ? fh : gh), dw ? fw : gw);
                wt[t] = valid ? wgt : 0.0f;
                int dc = min(max(di, 0), DD - 1);
                int hc = min(max(hi, 0), HH - 1);
                int wc = min(max(wi, 0), WW - 1);
                qa[t] = (dc * HH + hc) * WW + wc;
            }
            float acc0 = 0.0f, acc1 = 0.0f, acc2 = 0.0f;
            #pragma unroll
            for (int t = 0; t < 8; ++t) {
                acc0 = fadd(acc0, fmul(in[qa[t]], wt[t]));
                acc1 = fadd(acc1, fmul(in[S + qa[t]], wt[t]));
                acc2 = fadd(acc2, fmul(in[2 * S + qa[t]], wt[t]));
            }
            r0 = fadd(vd, acc0);
            r1 = fadd(vh, acc1);
            r2 = fadd(vw, acc2);
        }

        out[p] = r0; out[S + p] = r1; out[2 * S + p] = r2;
    }
}

// init+s1 fused: blend((dvf0,dvf1),w)/32 staged straight into LDS via float4.
__global__ __launch_bounds__(256) void fused_init_s1(const float* __restrict__ dvf0,
                                                     const float* __restrict__ dvf1,
                                                     const float* __restrict__ wp,
                                                     float* __restrict__ out) {
    constexpr int H = 1, RZ = 6, RY = 10, ROWS = 60, NCH4 = 600, CHF = 2400;
    __shared__ float smem[3 * CHF];
    float w = wp[0];
    float onew = fsub(1.0f, w);

    int b  = (blockIdx.x & 7) * 500 + (blockIdx.x >> 3);
    int ix = b % 5;
    int r  = b / 5;
    int iy = r % 20;
    int iz = r / 20;
    int x0 = ix << 5, y0 = iy << 3, z0 = iz << 2;
    int xs4 = x0 - 4, ys = y0 - H, zs = z0 - H;

    int tid = threadIdx.x;
    for (int c = tid; c < NCH4; c += 256) {
        int row = c / 10;
        int col = (c - row * 10) << 2;
        int rz  = row / RY;
        int ry  = row - rz * RY;
        int cz = min(max(zs + rz, 0), DD - 1);
        int cy = min(max(ys + ry, 0), HH - 1);
        int q  = min(max((cz * HH + cy) * WW + xs4 + col, 0), S - 4);
        #pragma unroll
        for (int ch = 0; ch < 3; ++ch) {
            float A[4], B[4], O[4];
            *(float4*)A = *(const float4*)(dvf0 + (size_t)ch * S + q);
            *(float4*)B = *(const float4*)(dvf1 + (size_t)ch * S + q);
            #pragma unroll
            for (int k = 0; k < 4; ++k)
                O[k] = fmul(fadd(fmul(A[k], onew), fmul(B[k], w)), 0.03125f);
            *(float4*)&smem[ch * CHF + row * 40 + col] = *(float4*)O;
        }
    }
    __syncthreads();

    int lane = tid & 63, wid = tid >> 6;
    int x = x0 | (lane & 31);
    int y = y0 | (wid << 1) | (lane >> 5);
    int lx = x - xs4;
    int ly = y - ys;

    for (int j = 0; j < 4; ++j) {
        int z = z0 + j;
        int p = (z * HH + y) * WW + x;
        int lc = ((j + H) * RY + ly) * 40 + lx;
        float vd = smem[lc], vh = smem[CHF + lc], vw = smem[2 * CHF + lc];

        float cd = fadd((float)z, vd);
        float ch = fadd((float)y, vh);
        float cw = fadd((float)x, vw);

        float d0 = floorf(cd), h0 = floorf(ch), w0 = floorf(cw);
        float fd = fsub(cd, d0), fh = fsub(ch, h0), fw = fsub(cw, w0);
        float gd = fsub(1.0f, fd), gh = fsub(1.0f, fh), gw = fsub(1.0f, fw);
        int d0i = (int)d0, h0i = (int)h0, w0i = (int)w0;

        int rd = d0i - zs, rh = h0i - ys, rw = w0i - xs4;
        bool ok = ((unsigned)rd < (unsigned)(RZ - 1))
                & ((unsigned)rh < (unsigned)(RY - 1))
                & ((unsigned)rw < 39u);

        float r0, r1, r2;
        if (ok) {
            bool vA0 = (d0i >= 0), vA1 = (d0i + 1 < DD);
            bool vB0 = (h0i >= 0), vB1 = (h0i + 1 < HH);
            bool vC0 = (w0i >= 0), vC1 = (w0i + 1 < WW);
            float wt[8];
            #pragma unroll
            for (int t = 0; t < 8; ++t) {
                int dd = t >> 2, dh = (t >> 1) & 1, dw = t & 1;
                bool valid = (dd ? vA1 : vA0) & (dh ? vB1 : vB0) & (dw ? vC1 : vC0);
                float wgt = fmul(fmul(dd ? fd : gd, dh ? fh : gh), dw ? fw : gw);
                wt[t] = valid ? wgt : 0.0f;
            }
            int l0 = (rd * RY + rh) * 40 + rw;
            const int off[8] = { 0, 1, 40, 41,
                                 RY * 40, RY * 40 + 1, (RY + 1) * 40, (RY + 1) * 40 + 1 };
            float acc0 = 0.0f, acc1 = 0.0f, acc2 = 0.0f;
            #pragma unroll
            for (int t = 0; t < 8; ++t) {
                int li = l0 + off[t];
                acc0 = fadd(acc0, fmul(smem[li], wt[t]));
                acc1 = fadd(acc1, fmul(smem[CHF + li], wt[t]));
                acc2 = fadd(acc2, fmul(smem[2 * CHF + li], wt[t]));
            }
            r0 = fadd(vd, acc0);
            r1 = fadd(vh, acc1);
            r2 = fadd(vw, acc2);
        } else {
            int   qa[8];
            float wt[8];
            #pragma unroll
            for (int t = 0; t < 8; ++t) {
                int dd = t >> 2, dh = (t >> 1) & 1, dw = t & 1;
                int di = d0i + dd, hi = h0i + dh, wi = w0i + dw;
                bool valid = (di >= 0) & (di < DD) & (hi >= 0) & (hi < HH)
                           & (wi >= 0) & (wi < WW);
                float wgt = fmul(fmul(dd ? fd : gd, dh ? fh : gh), dw ? fw : gw);
                wt[t] = valid ? wgt : 0.0f;
                int dc = min(max(di, 0), DD - 1);
                int hc = min(max(hi, 0), HH - 1);
                int wc = min(max(wi, 0), WW - 1);
                qa[t] = (dc * HH + hc) * WW + wc;
            }
            float acc0 = 0.0f, acc1 = 0.0f, acc2 = 0.0f;
            #pragma unroll
            for (int t = 0; t < 8; ++t) {
                float ga = fmul(fadd(fmul(dvf0[qa[t]], onew), fmul(dvf1[qa[t]], w)), 0.03125f);
                float gb = fmul(fadd(fmul(dvf0[S + qa[t]], onew), fmul(dvf1[S + qa[t]], w)), 0.03125f);
                float gc = fmul(fadd(fmul(dvf0[2 * S + qa[t]], onew), fmul(dvf1[2 * S + qa[t]], w)), 0.03125f);
                acc0 = fadd(acc0, fmul(ga, wt[t]));
                acc1 = fadd(acc1, fmul(gb, wt[t]));
                acc2 = fadd(acc2, fmul(gc, wt[t]));
            }
            r0 = fadd(vd, acc0);
            r1 = fadd(vh, acc1);
            r2 = fadd(vw, acc2);
        }

        out[p] = r0; out[S + p] = r1; out[2 * S + p] = r2;
    }
}

// s5 via channel-phased H=3 LDS (one 22.4 KB channel plane at a time) + image/
// label warp.  Tile 32x8x4, 4 voxels/thread, grid 4000.
__global__ __launch_bounds__(256) void final_phased(const float* __restrict__ ddf4,
                                                    const float* __restrict__ image,
                                                    const int* __restrict__ cav,
                                                    const int* __restrict__ cor,
                                                    float* __restrict__ outImg,
                                                    float* __restrict__ outDdf) {
    constexpr int RZ = 10, RY = 14, ROWS = 140, NCH4 = 1400, CHF = 5600;
    __shared__ float smem[CHF];

    int b  = (blockIdx.x & 7) * 500 + (blockIdx.x >> 3);
    int ix = b % 5;
    int r  = b / 5;
    int iy = r % 20;
    int iz = r / 20;
    int x0 = ix << 5, y0 = iy << 3, z0 = iz << 2;
    int xs4 = x0 - 4, ys = y0 - 3, zs = z0 - 3;

    int tid = threadIdx.x;
    int lane = tid & 63, wid = tid >> 6;
    int x = x0 | (lane & 31);
    int y = y0 | (wid << 1) | (lane >> 5);
    int p0 = (z0 * HH + y) * WW + x;

    // centers (coalesced)
    float ctd[4], cth[4], ctw[4];
    #pragma unroll
    for (int j = 0; j < 4; ++j) {
        ctd[j] = ddf4[p0 + j * PL];
        cth[j] = ddf4[S + p0 + j * PL];
        ctw[j] = ddf4[2 * S + p0 + j * PL];
    }

    // per-voxel precompute: weights + LDS base + ok mask
    float wt[4][8];
    int   l0[4];
    int   okm = 0;
    const int off[8] = { 0, 1, 40, 41,
                         RY * 40, RY * 40 + 1, (RY + 1) * 40, (RY + 1) * 40 + 1 };
    #pragma unroll
    for (int j = 0; j < 4; ++j) {
        int z = z0 + j;
        float cd = fadd((float)z, ctd[j]);
        float ch = fadd((float)y, cth[j]);
        float cw = fadd((float)x, ctw[j]);
        float d0 = floorf(cd), h0 = floorf(ch), w0 = floorf(cw);
        float fd = fsub(cd, d0), fh = fsub(ch, h0), fw = fsub(cw, w0);
        float gd = fsub(1.0f, fd), gh = fsub(1.0f, fh), gw = fsub(1.0f, fw);
        int d0i = (int)d0, h0i = (int)h0, w0i = (int)w0;

        bool vA0 = (d0i >= 0), vA1 = (d0i + 1 < DD);
        bool vB0 = (h0i >= 0), vB1 = (h0i + 1 < HH);
        bool vC0 = (w0i >= 0), vC1 = (w0i + 1 < WW);
        #pragma unroll
        for (int t = 0; t < 8; ++t) {
            int dd = t >> 2, dh = (t >> 1) & 1, dw = t & 1;
            bool valid = (dd ? vA1 : vA0) & (dh ? vB1 : vB0) & (dw ? vC1 : vC0);
            float wgt = fmul(fmul(dd ? fd : gd, dh ? fh : gh), dw ? fw : gw);
            wt[j][t] = valid ? wgt : 0.0f;
        }
        int rd = d0i - zs, rh = h0i - ys, rw = w0i - xs4;
        bool ok = ((unsigned)rd < (unsigned)(RZ - 1))
                & ((unsigned)rh < (unsigned)(RY - 1))
                & ((unsigned)rw < 39u);
        l0[j] = (rd * RY + rh) * 40 + rw;
        okm |= (ok ? 1 : 0) << j;
    }

    // three channel phases
    float acc[3][4] = {{0,0,0,0},{0,0,0,0},{0,0,0,0}};
    #pragma unroll
    for (int c = 0; c < 3; ++c) {
        if (c) __syncthreads();
        const float* src = ddf4 + (size_t)c * S;
        for (int cc = tid; cc < NCH4; cc += 256) {
            int row = cc / 10;
            int col = (cc - row * 10) << 2;
            int rz  = row / RY;
            int ry  = row - rz * RY;
            int cz = min(max(zs + rz, 0), DD - 1);
            int cy = min(max(ys + ry, 0), HH - 1);
            int q  = min(max((cz * HH + cy) * WW + xs4 + col, 0), S - 4);
            *(float4*)&smem[row * 40 + col] = *(const float4*)(src + q);
        }
        __syncthreads();
        #pragma unroll
        for (int j = 0; j < 4; ++j) {
            if ((okm >> j) & 1) {
                #pragma unroll
                for (int t = 0; t < 8; ++t)
                    acc[c][j] = fadd(acc[c][j], fmul(smem[l0[j] + off[t]], wt[j][t]));
            }
        }
    }

    // combine + (rare) fallback, then final image/label warp
    #pragma unroll
    for (int j = 0; j < 4; ++j) {
        int z = z0 + j;
        int p = p0 + j * PL;
        float r0, r1, r2;
        if ((okm >> j) & 1) {
            r0 = fadd(ctd[j], acc[0][j]);
            r1 = fadd(cth[j], acc[1][j]);
            r2 = fadd(ctw[j], acc[2][j]);
        } else {
            float cd = fadd((float)z, ctd[j]);
            float ch = fadd((float)y, cth[j]);
            float cw = fadd((float)x, ctw[j]);
            float d0 = floorf(cd), h0 = floorf(ch), w0 = floorf(cw);
            float fd = fsub(cd, d0), fh = fsub(ch, h0), fw = fsub(cw, w0);
            float gd = fsub(1.0f, fd), gh = fsub(1.0f, fh), gw = fsub(1.0f, fw);
            int d0i = (int)d0, h0i = (int)h0, w0i = (int)w0;
            int   qa[8];
            float wtf[8];
            #pragma unroll
            for (int t = 0; t < 8; ++t) {
                int dd = t >> 2, dh = (t >> 1) & 1, dw = t & 1;
                int di = d0i + dd, hi = h0i + dh, wi = w0i + dw;
                bool valid = (di >= 0) & (di < DD) & (hi >= 0) & (hi < HH)
                           & (wi >= 0) & (wi < WW);
                float wgt = fmul(fmul(dd ? fd : gd, dh ? fh : gh), dw ? fw : gw);
                wtf[t] = valid ? wgt : 0.0f;
                int dc = min(max(di, 0), DD - 1);
                int hc = min(max(hi, 0), HH - 1);
                int wc = min(max(wi, 0), WW - 1);
                qa[t] = (dc * HH + hc) * WW + wc;
            }
            float a0 = 0.0f, a1 = 0.0f, a2 = 0.0f;
            #pragma unroll
            for (int t = 0; t < 8; ++t) {
                a0 = fadd(a0, fmul(ddf4[qa[t]], wtf[t]));
                a1 = fadd(a1, fmul(ddf4[S + qa[t]], wtf[t]));
                a2 = fadd(a2, fmul(ddf4[2 * S + qa[t]], wtf[t]));
            }
            r0 = fadd(ctd[j], a0);
            r1 = fadd(cth[j], a1);
            r2 = fadd(ctw[j], a2);
        }
        outDdf[p] = r0; outDdf[S + p] = r1; outDdf[2 * S + p] = r2;

        // ---- image (trilinear) + labels (nearest) with ddf5
        float cd2 = fadd((float)z, r0);
        float ch2 = fadd((float)y, r1);
        float cw2 = fadd((float)x, r2);
        float d02 = floorf(cd2), h02 = floorf(ch2), w02 = floorf(cw2);
        float fd2 = fsub(cd2, d02), fh2 = fsub(ch2, h02), fw2 = fsub(cw2, w02);
        float gd2 = fsub(1.0f, fd2), gh2 = fsub(1.0f, fh2), gw2 = fsub(1.0f, fw2);
        int d2i = (int)d02, h2i = (int)h02, w2i = (int)w02;

        bool fast = ((unsigned)d2i < (unsigned)(DD - 1))
                  & ((unsigned)h2i < (unsigned)(HH - 1))
                  & ((unsigned)w2i < (unsigned)(WW - 1));
        if (fast) {
            const float* bp0 = image + (d2i * HH + h2i) * WW + w2i;
            const float* bp1 = bp0 + PL;
            float g[8];
            g[0] = bp0[0];      g[1] = bp0[1];
            g[2] = bp0[WW];     g[3] = bp0[WW + 1];
            g[4] = bp1[0];      g[5] = bp1[1];
            g[6] = bp1[WW];     g[7] = bp1[WW + 1];
            float w00 = fmul(gd2, gh2), w01 = fmul(gd2, fh2);
            float w10 = fmul(fd2, gh2), w11 = fmul(fd2, fh2);
            float wtf[8] = { fmul(w00, gw2), fmul(w00, fw2), fmul(w01, gw2), fmul(w01, fw2),
                             fmul(w10, gw2), fmul(w10, fw2), fmul(w11, gw2), fmul(w11, fw2) };
            float a = 0.0f;
            #pragma unroll
            for (int t = 0; t < 8; ++t) a = fadd(a, fmul(g[t], wtf[t]));
            outImg[p] = a;

            int di = (int)rintf(cd2), hi = (int)rintf(ch2), wi = (int)rintf(cw2);
            int q = (di * HH + hi) * WW + wi;
            outImg[S + p]     = (float)cav[q];
            outImg[2 * S + p] = (float)cor[q];
        } else {
            int   qb[8];
            float wtf[8];
            #pragma unroll
            for (int t = 0; t < 8; ++t) {
                int dd = t >> 2, dh = (t >> 1) & 1, dw = t & 1;
                int di = d2i + dd, hi = h2i + dh, wi = w2i + dw;
                bool valid = (di >= 0) & (di < DD) & (hi >= 0) & (hi < HH)
                           & (wi >= 0) & (wi < WW);
                float wgt = fmul(fmul(dd ? fd2 : gd2, dh ? fh2 : gh2), dw ? fw2 : gw2);
                wtf[t] = valid ? wgt : 0.0f;
                int dc = min(max(di, 0), DD - 1);
                int hc = min(max(hi, 0), HH - 1);
                int wc = min(max(wi, 0), WW - 1);
                qb[t] = (dc * HH + hc) * WW + wc;
            }
            float a = 0.0f;
            #pragma unroll
            for (int t = 0; t < 8; ++t) a = fadd(a, fmul(image[qb[t]], wtf[t]));
            outImg[p] = a;

            int di = (int)rintf(cd2), hi = (int)rintf(ch2), wi = (int)rintf(cw2);
            bool valid = (di >= 0) & (di < DD) & (hi >= 0) & (hi < HH)
                       & (wi >= 0) & (wi < WW);
            int dc = min(max(di, 0), DD - 1);
            int hc = min(max(hi, 0), HH - 1);
            int wc = min(max(wi, 0), WW - 1);
            int q = (dc * HH + hc) * WW + wc;
            outImg[S + p]     = valid ? (float)cav[q] : 0.0f;
            outImg[2 * S + p] = valid ? (float)cor[q] : 0.0f;
        }
    }
}

// ---- fallback path (d_ws too small): flat s5 + separate final, as verified r4.
__global__ __launch_bounds__(256) void warp_flat(const float* __restrict__ in,
                                                 float* __restrict__ out) {
    int b  = (blockIdx.x & 7) * 1000 + (blockIdx.x >> 3);
    int ix = b % 5;
    int r  = b / 5;
    int iy = r % 20;
    int iz = r / 20;
    int lane = threadIdx.x & 63, wid = threadIdx.x >> 6;
    int x  = (ix << 5) | (lane & 31);
    int y  = (iy << 3) | (wid << 1) | (lane >> 5);
    int z0 = iz << 1;
    int p0 = (z0 * HH + y) * WW + x;

    #pragma unroll
    for (int j = 0; j < 2; ++j) {
        int z = z0 + j;
        int p = p0 + j * PL;
        float vd = in[p], vh = in[S + p], vw = in[2 * S + p];
        float cd = fadd((float)z, vd);
        float ch = fadd((float)y, vh);
        float cw = fadd((float)x, vw);

        float d0 = floorf(cd), h0 = floorf(ch), w0 = floorf(cw);
        float fd = fsub(cd, d0), fh = fsub(ch, h0), fw = fsub(cw, w0);
        float gd = fsub(1.0f, fd), gh = fsub(1.0f, fh), gw = fsub(1.0f, fw);
        int d0i = (int)d0, h0i = (int)h0, w0i = (int)w0;

        int   qa[8];
        float wt[8];
        #pragma unroll
        for (int t = 0; t < 8; ++t) {
            int dd = t >> 2, dh = (t >> 1) & 1, dw = t & 1;
            int di = d0i + dd, hi = h0i + dh, wi = w0i + dw;
            bool valid = (di >= 0) & (di < DD) & (hi >= 0) & (hi < HH)
                       & (wi >= 0) & (wi < WW);
            float wgt = fmul(fmul(dd ? fd : gd, dh ? fh : gh), dw ? fw : gw);
            wt[t] = valid ? wgt : 0.0f;
            int dc = min(max(di, 0), DD - 1);
            int hc = min(max(hi, 0), HH - 1);
            int wc = min(max(wi, 0), WW - 1);
            qa[t] = (dc * HH + hc) * WW + wc;
        }
        float acc0 = 0.0f, acc1 = 0.0f, acc2 = 0.0f;
        #pragma unroll
        for (int t = 0; t < 8; ++t) {
            acc0 = fadd(acc0, fmul(in[qa[t]], wt[t]));
            acc1 = fadd(acc1, fmul(in[S + qa[t]], wt[t]));
            acc2 = fadd(acc2, fmul(in[2 * S + qa[t]], wt[t]));
        }
        out[p]         = fadd(vd, acc0);
        out[S + p]     = fadd(vh, acc1);
        out[2 * S + p] = fadd(vw, acc2);
    }
}

__global__ __launch_bounds__(256) void final_kernel(const float* __restrict__ ddf,
                                                    const float* __restrict__ image,
                                                    const int* __restrict__ cav,
                                                    const int* __restrict__ cor,
                                                    float* __restrict__ out) {
    int b  = (blockIdx.x & 7) * 1000 + (blockIdx.x >> 3);
    int ix = b % 5;
    int r  = b / 5;
    int iy = r % 20;
    int iz = r / 20;
    int lane = threadIdx.x & 63, wid = threadIdx.x >> 6;
    int x  = (ix << 5) | (lane & 31);
    int y  = (iy << 3) | (wid << 1) | (lane >> 5);
    int z0 = iz << 1;
    int p0 = (z0 * HH + y) * WW + x;

    #pragma unroll
    for (int j = 0; j < 2; ++j) {
        int z = z0 + j;
        int p = p0 + j * PL;
        float cd = fadd((float)z, ddf[p]);
        float ch = fadd((float)y, ddf[S + p]);
        float cw = fadd((float)x, ddf[2 * S + p]);

        float d0 = floorf(cd), h0 = floorf(ch), w0 = floorf(cw);
        float fd = fsub(cd, d0), fh = fsub(ch, h0), fw = fsub(cw, w0);
        float gd = fsub(1.0f, fd), gh = fsub(1.0f, fh), gw = fsub(1.0f, fw);
        int d0i = (int)d0, h0i = (int)h0, w0i = (int)w0;

        int   qa[8];
        float wt[8];
        #pragma unroll
        for (int t = 0; t < 8; ++t) {
            int dd = t >> 2, dh = (t >> 1) & 1, dw = t & 1;
            int di = d0i + dd, hi = h0i + dh, wi = w0i + dw;
            bool valid = (di >= 0) & (di < DD) & (hi >= 0) & (hi < HH)
                       & (wi >= 0) & (wi < WW);
            float wgt = fmul(fmul(dd ? fd : gd, dh ? fh : gh), dw ? fw : gw);
            wt[t] = valid ? wgt : 0.0f;
            int dc = min(max(di, 0), DD - 1);
            int hc = min(max(hi, 0), HH - 1);
            int wc = min(max(wi, 0), WW - 1);
            qa[t] = (dc * HH + hc) * WW + wc;
        }
        float acc = 0.0f;
        #pragma unroll
        for (int t = 0; t < 8; ++t) acc = fadd(acc, fmul(image[qa[t]], wt[t]));
        out[p] = acc;

        int di = (int)rintf(cd), hi = (int)rintf(ch), wi = (int)rintf(cw);
        bool valid = (di >= 0) & (di < DD) & (hi >= 0) & (hi < HH)
                   & (wi >= 0) & (wi < WW);
        int dc = min(max(di, 0), DD - 1);
        int hc = min(max(hi, 0), HH - 1);
        int wc = min(max(wi, 0), WW - 1);
        int q = (dc * HH + hc) * WW + wc;
        out[S + p]     = valid ? (float)cav[q] : 0.0f;
        out[2 * S + p] = valid ? (float)cor[q] : 0.0f;
    }
}

extern "C" void kernel_launch(void* const* d_in, const int* in_sizes, int n_in,
                              void* d_out, int out_size, void* d_ws, size_t ws_size,
                              hipStream_t stream) {
    const float* dvf0   = (const float*)d_in[0];
    const float* dvf1   = (const float*)d_in[1];
    const float* image  = (const float*)d_in[2];
    const int*   cav    = (const int*)d_in[3];
    const int*   cor    = (const int*)d_in[4];
    const float* w      = (const float*)d_in[5];

    float* out  = (float*)d_out;
    float* bufA = out;                    // ends as img, cav, cor
    float* bufB = out + (size_t)3 * S;    // ends as ddf5 (planar)
    float* bufC = (float*)d_ws;           // ddf4 scratch (if big enough)
    bool useWs = (d_ws != nullptr) && (ws_size >= (size_t)3 * S * sizeof(float));

    fused_init_s1<<<4000, 256, 0, stream>>>(dvf0, dvf1, w, bufB);     // ddf1
    warp_step<1><<<4000, 256, 0, stream>>>(bufB, bufA);               // ddf2
    warp_step<1><<<4000, 256, 0, stream>>>(bufA, bufB);               // ddf3
    if (useWs) {
        warp_step<2><<<4000, 256, 0, stream>>>(bufB, bufC);           // ddf4 -> ws
        final_phased<<<4000, 256, 0, stream>>>(bufC, image, cav, cor, bufA, bufB);
    } else {
        warp_step<2><<<4000, 256, 0, stream>>>(bufB, bufA);           // ddf4
        warp_flat<<<8000, 256, 0, stream>>>(bufA, bufB);              // ddf5
        final_kernel<<<8000, 256, 0, stream>>>(bufB, image, cav, cor, bufA);
    }
}

// Round 6
// 366.546 us; speedup vs baseline: 1.3896x; 1.0280x over previous
//
#include <hip/hip_runtime.h>

#define DD 160
#define HH 160
#define WW 160
#define PL (HH*WW)       // one z-plane = 25600 voxels
#define S (DD*PL)        // 4,096,000 voxels

__device__ __forceinline__ float fmul(float a, float b){ return __fmul_rn(a,b); }
__device__ __forceinline__ float fadd(float a, float b){ return __fadd_rn(a,b); }
__device__ __forceinline__ float fsub(float a, float b){ return __fsub_rn(a,b); }

// async global->LDS DMA, 16B per lane.  LDS dest is wave-uniform base + lane*16,
// which matches our LINEAR chunk layout (chunk c -> LDS byte 16c, c = base+lane).
// Global src is per-lane (clamped addresses fine).  Completion: __syncthreads()
// drains vmcnt.
__device__ __forceinline__ void dma16(const float* g, float* l) {
    __builtin_amdgcn_global_load_lds(
        (const __attribute__((address_space(1))) unsigned int*)g,
        (__attribute__((address_space(3))) unsigned int*)l,
        16, 0, 0);
}

// ---------------------------------------------------------------------------
// LDS tiles: 40-float (160B) rows spanning x in [x0-4, x0+36), 16B aligned.
// x-halo slots outside the volume hold raw neighbors (only multiplied by +0.0);
// all staged addresses clamped to [0, S-4] (written, finite).
//   fused_init_s1 : blend staged into LDS (reg path, H=1)      -> ddf1
//   warp_step<1>  : ddf2, ddf3   (28.8 KB, DMA-staged)
//   warp_step<2>  : ddf4         (46.1 KB, DMA-staged)
//   final_phased  : s5 via channel-phased H=3 LDS, DOUBLE-BUFFERED with
//                   DMA prefetch of phase c+1 under gather of phase c,
//                   + image/label warp, one dispatch.
// ---------------------------------------------------------------------------

// out = in + trilinear_warp(in, in); planar in/out; LDS DMA-staged gather.
// Tile 32(x) x 8(y) x 4(z); grid 5*20*40 = 4000 blocks, XCD-swizzled.
template<int H>
__global__ __launch_bounds__(256) void warp_step(const float* __restrict__ in,
                                                 float* __restrict__ out) {
    constexpr int RZ = 4 + 2 * H;
    constexpr int RY = 8 + 2 * H;
    constexpr int ROWS = RZ * RY;
    constexpr int NCH4 = ROWS * 10;       // float4 chunks per channel
    constexpr int CHF  = ROWS * 40;       // floats per channel
    __shared__ __align__(16) float smem[3 * CHF];

    int b  = (blockIdx.x & 7) * 500 + (blockIdx.x >> 3);
    int ix = b % 5;
    int r  = b / 5;
    int iy = r % 20;
    int iz = r / 20;                 // 0..39
    int x0 = ix << 5, y0 = iy << 3, z0 = iz << 2;
    int xs4 = x0 - 4, ys = y0 - H, zs = z0 - H;

    int tid = threadIdx.x;
    for (int c = tid; c < NCH4; c += 256) {
        int row = c / 10;
        int col = (c - row * 10) << 2;
        int rz  = row / RY;
        int ry  = row - rz * RY;
        int cz = min(max(zs + rz, 0), DD - 1);
        int cy = min(max(ys + ry, 0), HH - 1);
        int q  = min(max((cz * HH + cy) * WW + xs4 + col, 0), S - 4);
        dma16(in + q,         smem + (c << 2));
        dma16(in + S + q,     smem + CHF + (c << 2));
        dma16(in + 2 * S + q, smem + 2 * CHF + (c << 2));
    }
    __syncthreads();

    int lane = tid & 63, wid = tid >> 6;
    int x = x0 | (lane & 31);
    int y = y0 | (wid << 1) | (lane >> 5);
    int lx = x - xs4;                 // 4..35
    int ly = y - ys;

    for (int j = 0; j < 4; ++j) {
        int z = z0 + j;
        int p = (z * HH + y) * WW + x;
        int lc = ((j + H) * RY + ly) * 40 + lx;
        float vd = smem[lc], vh = smem[CHF + lc], vw = smem[2 * CHF + lc];

        float cd = fadd((float)z, vd);
        float ch = fadd((float)y, vh);
        float cw = fadd((float)x, vw);

        float d0 = floorf(cd), h0 = floorf(ch), w0 = floorf(cw);
        float fd = fsub(cd, d0), fh = fsub(ch, h0), fw = fsub(cw, w0);
        float gd = fsub(1.0f, fd), gh = fsub(1.0f, fh), gw = fsub(1.0f, fw);
        int d0i = (int)d0, h0i = (int)h0, w0i = (int)w0;

        int rd = d0i - zs, rh = h0i - ys, rw = w0i - xs4;
        bool ok = ((unsigned)rd < (unsigned)(RZ - 1))
                & ((unsigned)rh < (unsigned)(RY - 1))
                & ((unsigned)rw < 39u);

        float r0, r1, r2;
        if (ok) {
            bool vA0 = (d0i >= 0), vA1 = (d0i + 1 < DD);
            bool vB0 = (h0i >= 0), vB1 = (h0i + 1 < HH);
            bool vC0 = (w0i >= 0), vC1 = (w0i + 1 < WW);
            float wt[8];
            #pragma unroll
            for (int t = 0; t < 8; ++t) {
                int dd = t >> 2, dh = (t >> 1) & 1, dw = t & 1;
                bool valid = (dd ? vA1 : vA0) & (dh ? vB1 : vB0) & (dw ? vC1 : vC0);
                float wgt = fmul(fmul(dd ? fd : gd, dh ? fh : gh), dw ? fw : gw);
                wt[t] = valid ? wgt : 0.0f;
            }
            int l0 = (rd * RY + rh) * 40 + rw;
            const int off[8] = { 0, 1, 40, 41,
                                 RY * 40, RY * 40 + 1, (RY + 1) * 40, (RY + 1) * 40 + 1 };
            float acc0 = 0.0f, acc1 = 0.0f, acc2 = 0.0f;
            #pragma unroll
            for (int t = 0; t < 8; ++t) {
                int li = l0 + off[t];
                acc0 = fadd(acc0, fmul(smem[li], wt[t]));
                acc1 = fadd(acc1, fmul(smem[CHF + li], wt[t]));
                acc2 = fadd(acc2, fmul(smem[2 * CHF + li], wt[t]));
            }
            r0 = fadd(vd, acc0);
            r1 = fadd(vh, acc1);
            r2 = fadd(vw, acc2);
        } else {
            int   qa[8];
            float wt[8];
            #pragma unroll
            for (int t = 0; t < 8; ++t) {
                int dd = t >> 2, dh = (t >> 1) & 1, dw = t & 1;
                int di = d0i + dd, hi = h0i + dh, wi = w0i + dw;
                bool valid = (di >= 0) & (di < DD) & (hi >= 0) & (hi < HH)
                           & (wi >= 0) & (wi < WW);
                float wgt = fmul(fmul(dd ? fd : gd, dh ? fh : gh), dw ? fw : gw);
                wt[t] = valid ? wgt : 0.0f;
                int dc = min(max(di, 0), DD - 1);
                int hc = min(max(hi, 0), HH - 1);
                int wc = min(max(wi, 0), WW - 1);
                qa[t] = (dc * HH + hc) * WW + wc;
            }
            float acc0 = 0.0f, acc1 = 0.0f, acc2 = 0.0f;
            #pragma unroll
            for (int t = 0; t < 8; ++t) {
                acc0 = fadd(acc0, fmul(in[qa[t]], wt[t]));
                acc1 = fadd(acc1, fmul(in[S + qa[t]], wt[t]));
                acc2 = fadd(acc2, fmul(in[2 * S + qa[t]], wt[t]));
            }
            r0 = fadd(vd, acc0);
            r1 = fadd(vh, acc1);
            r2 = fadd(vw, acc2);
        }

        out[p] = r0; out[S + p] = r1; out[2 * S + p] = r2;
    }
}

// init+s1 fused: blend((dvf0,dvf1),w)/32 staged into LDS via float4 regs
// (compute during staging -> cannot DMA).
__global__ __launch_bounds__(256) void fused_init_s1(const float* __restrict__ dvf0,
                                                     const float* __restrict__ dvf1,
                                                     const float* __restrict__ wp,
                                                     float* __restrict__ out) {
    constexpr int H = 1, RZ = 6, RY = 10, ROWS = 60, NCH4 = 600, CHF = 2400;
    __shared__ __align__(16) float smem[3 * CHF];
    float w = wp[0];
    float onew = fsub(1.0f, w);

    int b  = (blockIdx.x & 7) * 500 + (blockIdx.x >> 3);
    int ix = b % 5;
    int r  = b / 5;
    int iy = r % 20;
    int iz = r / 20;
    int x0 = ix << 5, y0 = iy << 3, z0 = iz << 2;
    int xs4 = x0 - 4, ys = y0 - H, zs = z0 - H;

    int tid = threadIdx.x;
    for (int c = tid; c < NCH4; c += 256) {
        int row = c / 10;
        int col = (c - row * 10) << 2;
        int rz  = row / RY;
        int ry  = row - rz * RY;
        int cz = min(max(zs + rz, 0), DD - 1);
        int cy = min(max(ys + ry, 0), HH - 1);
        int q  = min(max((cz * HH + cy) * WW + xs4 + col, 0), S - 4);
        #pragma unroll
        for (int ch = 0; ch < 3; ++ch) {
            float A[4], B[4], O[4];
            *(float4*)A = *(const float4*)(dvf0 + (size_t)ch * S + q);
            *(float4*)B = *(const float4*)(dvf1 + (size_t)ch * S + q);
            #pragma unroll
            for (int k = 0; k < 4; ++k)
                O[k] = fmul(fadd(fmul(A[k], onew), fmul(B[k], w)), 0.03125f);
            *(float4*)&smem[ch * CHF + row * 40 + col] = *(float4*)O;
        }
    }
    __syncthreads();

    int lane = tid & 63, wid = tid >> 6;
    int x = x0 | (lane & 31);
    int y = y0 | (wid << 1) | (lane >> 5);
    int lx = x - xs4;
    int ly = y - ys;

    for (int j = 0; j < 4; ++j) {
        int z = z0 + j;
        int p = (z * HH + y) * WW + x;
        int lc = ((j + H) * RY + ly) * 40 + lx;
        float vd = smem[lc], vh = smem[CHF + lc], vw = smem[2 * CHF + lc];

        float cd = fadd((float)z, vd);
        float ch = fadd((float)y, vh);
        float cw = fadd((float)x, vw);

        float d0 = floorf(cd), h0 = floorf(ch), w0 = floorf(cw);
        float fd = fsub(cd, d0), fh = fsub(ch, h0), fw = fsub(cw, w0);
        float gd = fsub(1.0f, fd), gh = fsub(1.0f, fh), gw = fsub(1.0f, fw);
        int d0i = (int)d0, h0i = (int)h0, w0i = (int)w0;

        int rd = d0i - zs, rh = h0i - ys, rw = w0i - xs4;
        bool ok = ((unsigned)rd < (unsigned)(RZ - 1))
                & ((unsigned)rh < (unsigned)(RY - 1))
                & ((unsigned)rw < 39u);

        float r0, r1, r2;
        if (ok) {
            bool vA0 = (d0i >= 0), vA1 = (d0i + 1 < DD);
            bool vB0 = (h0i >= 0), vB1 = (h0i + 1 < HH);
            bool vC0 = (w0i >= 0), vC1 = (w0i + 1 < WW);
            float wt[8];
            #pragma unroll
            for (int t = 0; t < 8; ++t) {
                int dd = t >> 2, dh = (t >> 1) & 1, dw = t & 1;
                bool valid = (dd ? vA1 : vA0) & (dh ? vB1 : vB0) & (dw ? vC1 : vC0);
                float wgt = fmul(fmul(dd ? fd : gd, dh ? fh : gh), dw ? fw : gw);
                wt[t] = valid ? wgt : 0.0f;
            }
            int l0 = (rd * RY + rh) * 40 + rw;
            const int off[8] = { 0, 1, 40, 41,
                                 RY * 40, RY * 40 + 1, (RY + 1) * 40, (RY + 1) * 40 + 1 };
            float acc0 = 0.0f, acc1 = 0.0f, acc2 = 0.0f;
            #pragma unroll
            for (int t = 0; t < 8; ++t) {
                int li = l0 + off[t];
                acc0 = fadd(acc0, fmul(smem[li], wt[t]));
                acc1 = fadd(acc1, fmul(smem[CHF + li], wt[t]));
                acc2 = fadd(acc2, fmul(smem[2 * CHF + li], wt[t]));
            }
            r0 = fadd(vd, acc0);
            r1 = fadd(vh, acc1);
            r2 = fadd(vw, acc2);
        } else {
            int   qa[8];
            float wt[8];
            #pragma unroll
            for (int t = 0; t < 8; ++t) {
                int dd = t >> 2, dh = (t >> 1) & 1, dw = t & 1;
                int di = d0i + dd, hi = h0i + dh, wi = w0i + dw;
                bool valid = (di >= 0) & (di < DD) & (hi >= 0) & (hi < HH)
                           & (wi >= 0) & (wi < WW);
                float wgt = fmul(fmul(dd ? fd : gd, dh ? fh : gh), dw ? fw : gw);
                wt[t] = valid ? wgt : 0.0f;
                int dc = min(max(di, 0), DD - 1);
                int hc = min(max(hi, 0), HH - 1);
                int wc = min(max(wi, 0), WW - 1);
                qa[t] = (dc * HH + hc) * WW + wc;
            }
            float acc0 = 0.0f, acc1 = 0.0f, acc2 = 0.0f;
            #pragma unroll
            for (int t = 0; t < 8; ++t) {
                float ga = fmul(fadd(fmul(dvf0[qa[t]], onew), fmul(dvf1[qa[t]], w)), 0.03125f);
                float gb = fmul(fadd(fmul(dvf0[S + qa[t]], onew), fmul(dvf1[S + qa[t]], w)), 0.03125f);
                float gc = fmul(fadd(fmul(dvf0[2 * S + qa[t]], onew), fmul(dvf1[2 * S + qa[t]], w)), 0.03125f);
                acc0 = fadd(acc0, fmul(ga, wt[t]));
                acc1 = fadd(acc1, fmul(gb, wt[t]));
                acc2 = fadd(acc2, fmul(gc, wt[t]));
            }
            r0 = fadd(vd, acc0);
            r1 = fadd(vh, acc1);
            r2 = fadd(vw, acc2);
        }

        out[p] = r0; out[S + p] = r1; out[2 * S + p] = r2;
    }
}

// s5 via channel-phased H=3 LDS, DOUBLE-BUFFERED: DMA of phase c+1 issued
// before gather of phase c; __syncthreads drains it at phase end.  Per-channel
// ddf5 stores inside the phase.  Then image/label warp.  Tile 32x8x4, grid 4000.
__global__ __launch_bounds__(256) void final_phased(const float* __restrict__ ddf4,
                                                    const float* __restrict__ image,
                                                    const int* __restrict__ cav,
                                                    const int* __restrict__ cor,
                                                    float* __restrict__ outImg,
                                                    float* __restrict__ outDdf) {
    constexpr int RZ = 10, RY = 14, ROWS = 140, NCH4 = 1400, CHF = 5600;
    __shared__ __align__(16) float smem[2 * CHF];   // double buffer, 44.8 KB

    int b  = (blockIdx.x & 7) * 500 + (blockIdx.x >> 3);
    int ix = b % 5;
    int r  = b / 5;
    int iy = r % 20;
    int iz = r / 20;
    int x0 = ix << 5, y0 = iy << 3, z0 = iz << 2;
    int xs4 = x0 - 4, ys = y0 - 3, zs = z0 - 3;

    int tid = threadIdx.x;
    int lane = tid & 63, wid = tid >> 6;
    int x = x0 | (lane & 31);
    int y = y0 | (wid << 1) | (lane >> 5);
    int p0 = (z0 * HH + y) * WW + x;

    // ---- issue phase-0 staging DMA immediately (flight time covered by setup)
    #pragma unroll 1
    for (int cc = tid; cc < NCH4; cc += 256) {
        int row = cc / 10;
        int col = (cc - row * 10) << 2;
        int rz  = row / RY;
        int ry  = row - rz * RY;
        int cz = min(max(zs + rz, 0), DD - 1);
        int cy = min(max(ys + ry, 0), HH - 1);
        int q  = min(max((cz * HH + cy) * WW + xs4 + col, 0), S - 4);
        dma16(ddf4 + q, smem + (cc << 2));
    }

    // centers (coalesced)
    float ctd[4], cth[4], ctw[4];
    #pragma unroll
    for (int j = 0; j < 4; ++j) {
        ctd[j] = ddf4[p0 + j * PL];
        cth[j] = ddf4[S + p0 + j * PL];
        ctw[j] = ddf4[2 * S + p0 + j * PL];
    }

    // per-voxel precompute: weights + LDS base + ok mask
    float wt[4][8];
    int   l0[4];
    int   okm = 0;
    const int off[8] = { 0, 1, 40, 41,
                         RY * 40, RY * 40 + 1, (RY + 1) * 40, (RY + 1) * 40 + 1 };
    #pragma unroll
    for (int j = 0; j < 4; ++j) {
        int z = z0 + j;
        float cd = fadd((float)z, ctd[j]);
        float ch = fadd((float)y, cth[j]);
        float cw = fadd((float)x, ctw[j]);
        float d0 = floorf(cd), h0 = floorf(ch), w0 = floorf(cw);
        float fd = fsub(cd, d0), fh = fsub(ch, h0), fw = fsub(cw, w0);
        float gd = fsub(1.0f, fd), gh = fsub(1.0f, fh), gw = fsub(1.0f, fw);
        int d0i = (int)d0, h0i = (int)h0, w0i = (int)w0;

        bool vA0 = (d0i >= 0), vA1 = (d0i + 1 < DD);
        bool vB0 = (h0i >= 0), vB1 = (h0i + 1 < HH);
        bool vC0 = (w0i >= 0), vC1 = (w0i + 1 < WW);
        #pragma unroll
        for (int t = 0; t < 8; ++t) {
            int dd = t >> 2, dh = (t >> 1) & 1, dw = t & 1;
            bool valid = (dd ? vA1 : vA0) & (dh ? vB1 : vB0) & (dw ? vC1 : vC0);
            float wgt = fmul(fmul(dd ? fd : gd, dh ? fh : gh), dw ? fw : gw);
            wt[j][t] = valid ? wgt : 0.0f;
        }
        int rd = d0i - zs, rh = h0i - ys, rw = w0i - xs4;
        bool ok = ((unsigned)rd < (unsigned)(RZ - 1))
                & ((unsigned)rh < (unsigned)(RY - 1))
                & ((unsigned)rw < 39u);
        l0[j] = (rd * RY + rh) * 40 + rw;
        okm |= (ok ? 1 : 0) << j;
    }

    // rare fallback (analytic halo bound violated): exact global gather, all ch
    float fb[3][4];
    if (okm != 15) {
        #pragma unroll
        for (int j = 0; j < 4; ++j) {
            if (!((okm >> j) & 1)) {
                int z = z0 + j;
                float cd = fadd((float)z, ctd[j]);
                float ch = fadd((float)y, cth[j]);
                float cw = fadd((float)x, ctw[j]);
                float d0 = floorf(cd), h0 = floorf(ch), w0 = floorf(cw);
                float fd = fsub(cd, d0), fh = fsub(ch, h0), fw = fsub(cw, w0);
                float gd = fsub(1.0f, fd), gh = fsub(1.0f, fh), gw = fsub(1.0f, fw);
                int d0i = (int)d0, h0i = (int)h0, w0i = (int)w0;
                int   qa[8];
                float wtf[8];
                #pragma unroll
                for (int t = 0; t < 8; ++t) {
                    int dd = t >> 2, dh = (t >> 1) & 1, dw = t & 1;
                    int di = d0i + dd, hi = h0i + dh, wi = w0i + dw;
                    bool valid = (di >= 0) & (di < DD) & (hi >= 0) & (hi < HH)
                               & (wi >= 0) & (wi < WW);
                    float wgt = fmul(fmul(dd ? fd : gd, dh ? fh : gh), dw ? fw : gw);
                    wtf[t] = valid ? wgt : 0.0f;
                    int dc = min(max(di, 0), DD - 1);
                    int hc = min(max(hi, 0), HH - 1);
                    int wc = min(max(wi, 0), WW - 1);
                    qa[t] = (dc * HH + hc) * WW + wc;
                }
                float a0 = 0.0f, a1 = 0.0f, a2 = 0.0f;
                #pragma unroll
                for (int t = 0; t < 8; ++t) {
                    a0 = fadd(a0, fmul(ddf4[qa[t]], wtf[t]));
                    a1 = fadd(a1, fmul(ddf4[S + qa[t]], wtf[t]));
                    a2 = fadd(a2, fmul(ddf4[2 * S + qa[t]], wtf[t]));
                }
                fb[0][j] = a0; fb[1][j] = a1; fb[2][j] = a2;
            }
        }
    }

    __syncthreads();   // phase-0 DMA complete

    // ---- three channel phases, double-buffered
    float rr[3][4];
    #pragma unroll
    for (int c = 0; c < 3; ++c) {
        // prefetch phase c+1 into the other buffer (DMA, in flight under gather)
        if (c < 2) {
            const float* src = ddf4 + (size_t)(c + 1) * S;
            float* buf = smem + ((c + 1) & 1) * CHF;
            #pragma unroll 1
            for (int cc = tid; cc < NCH4; cc += 256) {
                int row = cc / 10;
                int col = (cc - row * 10) << 2;
                int rz  = row / RY;
                int ry  = row - rz * RY;
                int cz = min(max(zs + rz, 0), DD - 1);
                int cy = min(max(ys + ry, 0), HH - 1);
                int q  = min(max((cz * HH + cy) * WW + xs4 + col, 0), S - 4);
                dma16(src + q, buf + (cc << 2));
            }
        }
        // gather phase c
        const float* g = smem + (c & 1) * CHF;
        float ctr_c = 0.0f;
        #pragma unroll
        for (int j = 0; j < 4; ++j) {
            float acc = 0.0f;
            if ((okm >> j) & 1) {
                #pragma unroll
                for (int t = 0; t < 8; ++t)
                    acc = fadd(acc, fmul(g[l0[j] + off[t]], wt[j][t]));
                float ctr = (c == 0) ? ctd[j] : (c == 1) ? cth[j] : ctw[j];
                rr[c][j] = fadd(ctr, acc);
            } else {
                float ctr = (c == 0) ? ctd[j] : (c == 1) ? cth[j] : ctw[j];
                rr[c][j] = fadd(ctr, fb[c][j]);
            }
            outDdf[(size_t)c * S + p0 + j * PL] = rr[c][j];
        }
        (void)ctr_c;
        __syncthreads();   // drains DMA for c+1; everyone done reading buf c
    }

    // ---- image (trilinear) + labels (nearest) with ddf5
    #pragma unroll
    for (int j = 0; j < 4; ++j) {
        int z = z0 + j;
        int p = p0 + j * PL;
        float r0 = rr[0][j], r1 = rr[1][j], r2 = rr[2][j];

        float cd2 = fadd((float)z, r0);
        float ch2 = fadd((float)y, r1);
        float cw2 = fadd((float)x, r2);
        float d02 = floorf(cd2), h02 = floorf(ch2), w02 = floorf(cw2);
        float fd2 = fsub(cd2, d02), fh2 = fsub(ch2, h02), fw2 = fsub(cw2, w02);
        float gd2 = fsub(1.0f, fd2), gh2 = fsub(1.0f, fh2), gw2 = fsub(1.0f, fw2);
        int d2i = (int)d02, h2i = (int)h02, w2i = (int)w02;

        bool fast = ((unsigned)d2i < (unsigned)(DD - 1))
                  & ((unsigned)h2i < (unsigned)(HH - 1))
                  & ((unsigned)w2i < (unsigned)(WW - 1));
        if (fast) {
            const float* bp0 = image + (d2i * HH + h2i) * WW + w2i;
            const float* bp1 = bp0 + PL;
            float g[8];
            g[0] = bp0[0];      g[1] = bp0[1];
            g[2] = bp0[WW];     g[3] = bp0[WW + 1];
            g[4] = bp1[0];      g[5] = bp1[1];
            g[6] = bp1[WW];     g[7] = bp1[WW + 1];
            float w00 = fmul(gd2, gh2), w01 = fmul(gd2, fh2);
            float w10 = fmul(fd2, gh2), w11 = fmul(fd2, fh2);
            float wtf[8] = { fmul(w00, gw2), fmul(w00, fw2), fmul(w01, gw2), fmul(w01, fw2),
                             fmul(w10, gw2), fmul(w10, fw2), fmul(w11, gw2), fmul(w11, fw2) };
            float a = 0.0f;
            #pragma unroll
            for (int t = 0; t < 8; ++t) a = fadd(a, fmul(g[t], wtf[t]));
            outImg[p] = a;

            int di = (int)rintf(cd2), hi = (int)rintf(ch2), wi = (int)rintf(cw2);
            int q = (di * HH + hi) * WW + wi;
            outImg[S + p]     = (float)cav[q];
            outImg[2 * S + p] = (float)cor[q];
        } else {
            int   qb[8];
            float wtf[8];
            #pragma unroll
            for (int t = 0; t < 8; ++t) {
                int dd = t >> 2, dh = (t >> 1) & 1, dw = t & 1;
                int di = d2i + dd, hi = h2i + dh, wi = w2i + dw;
                bool valid = (di >= 0) & (di < DD) & (hi >= 0) & (hi < HH)
                           & (wi >= 0) & (wi < WW);
                float wgt = fmul(fmul(dd ? fd2 : gd2, dh ? fh2 : gh2), dw ? fw2 : gw2);
                wtf[t] = valid ? wgt : 0.0f;
                int dc = min(max(di, 0), DD - 1);
                int hc = min(max(hi, 0), HH - 1);
                int wc = min(max(wi, 0), WW - 1);
                qb[t] = (dc * HH + hc) * WW + wc;
            }
            float a = 0.0f;
            #pragma unroll
            for (int t = 0; t < 8; ++t) a = fadd(a, fmul(image[qb[t]], wtf[t]));
            outImg[p] = a;

            int di = (int)rintf(cd2), hi = (int)rintf(ch2), wi = (int)rintf(cw2);
            bool valid = (di >= 0) & (di < DD) & (hi >= 0) & (hi < HH)
                       & (wi >= 0) & (wi < WW);
            int dc = min(max(di, 0), DD - 1);
            int hc = min(max(hi, 0), HH - 1);
            int wc = min(max(wi, 0), WW - 1);
            int q = (dc * HH + hc) * WW + wc;
            outImg[S + p]     = valid ? (float)cav[q] : 0.0f;
            outImg[2 * S + p] = valid ? (float)cor[q] : 0.0f;
        }
    }
}

// ---- fallback path (d_ws too small): flat s5 + separate final.
__global__ __launch_bounds__(256) void warp_flat(const float* __restrict__ in,
                                                 float* __restrict__ out) {
    int b  = (blockIdx.x & 7) * 1000 + (blockIdx.x >> 3);
    int ix = b % 5;
    int r  = b / 5;
    int iy = r % 20;
    int iz = r / 20;
    int lane = threadIdx.x & 63, wid = threadIdx.x >> 6;
    int x  = (ix << 5) | (lane & 31);
    int y  = (iy << 3) | (wid << 1) | (lane >> 5);
    int z0 = iz << 1;
    int p0 = (z0 * HH + y) * WW + x;

    #pragma unroll
    for (int j = 0; j < 2; ++j) {
        int z = z0 + j;
        int p = p0 + j * PL;
        float vd = in[p], vh = in[S + p], vw = in[2 * S + p];
        float cd = fadd((float)z, vd);
        float ch = fadd((float)y, vh);
        float cw = fadd((float)x, vw);

        float d0 = floorf(cd), h0 = floorf(ch), w0 = floorf(cw);
        float fd = fsub(cd, d0), fh = fsub(ch, h0), fw = fsub(cw, w0);
        float gd = fsub(1.0f, fd), gh = fsub(1.0f, fh), gw = fsub(1.0f, fw);
        int d0i = (int)d0, h0i = (int)h0, w0i = (int)w0;

        int   qa[8];
        float wt[8];
        #pragma unroll
        for (int t = 0; t < 8; ++t) {
            int dd = t >> 2, dh = (t >> 1) & 1, dw = t & 1;
            int di = d0i + dd, hi = h0i + dh, wi = w0i + dw;
            bool valid = (di >= 0) & (di < DD) & (hi >= 0) & (hi < HH)
                       & (wi >= 0) & (wi < WW);
            float wgt = fmul(fmul(dd ? fd : gd, dh ? fh : gh), dw ? fw : gw);
            wt[t] = valid ? wgt : 0.0f;
            int dc = min(max(di, 0), DD - 1);
            int hc = min(max(hi, 0), HH - 1);
            int wc = min(max(wi, 0), WW - 1);
            qa[t] = (dc * HH + hc) * WW + wc;
        }
        float acc0 = 0.0f, acc1 = 0.0f, acc2 = 0.0f;
        #pragma unroll
        for (int t = 0; t < 8; ++t) {
            acc0 = fadd(acc0, fmul(in[qa[t]], wt[t]));
            acc1 = fadd(acc1, fmul(in[S + qa[t]], wt[t]));
            acc2 = fadd(acc2, fmul(in[2 * S + qa[t]], wt[t]));
        }
        out[p]         = fadd(vd, acc0);
        out[S + p]     = fadd(vh, acc1);
        out[2 * S + p] = fadd(vw, acc2);
    }
}

__global__ __launch_bounds__(256) void final_kernel(const float* __restrict__ ddf,
                                                    const float* __restrict__ image,
                                                    const int* __restrict__ cav,
                                                    const int* __restrict__ cor,
                                                    float* __restrict__ out) {
    int b  = (blockIdx.x & 7) * 1000 + (blockIdx.x >> 3);
    int ix = b % 5;
    int r  = b / 5;
    int iy = r % 20;
    int iz = r / 20;
    int lane = threadIdx.x & 63, wid = threadIdx.x >> 6;
    int x  = (ix << 5) | (lane & 31);
    int y  = (iy << 3) | (wid << 1) | (lane >> 5);
    int z0 = iz << 1;
    int p0 = (z0 * HH + y) * WW + x;

    #pragma unroll
    for (int j = 0; j < 2; ++j) {
        int z = z0 + j;
        int p = p0 + j * PL;
        float cd = fadd((float)z, ddf[p]);
        float ch = fadd((float)y, ddf[S + p]);
        float cw = fadd((float)x, ddf[2 * S + p]);

        float d0 = floorf(cd), h0 = floorf(ch), w0 = floorf(cw);
        float fd = fsub(cd, d0), fh = fsub(ch, h0), fw = fsub(cw, w0);
        float gd = fsub(1.0f, fd), gh = fsub(1.0f, fh), gw = fsub(1.0f, fw);
        int d0i = (int)d0, h0i = (int)h0, w0i = (int)w0;

        int   qa[8];
        float wt[8];
        #pragma unroll
        for (int t = 0; t < 8; ++t) {
            int dd = t >> 2, dh = (t >> 1) & 1, dw = t & 1;
            int di = d0i + dd, hi = h0i + dh, wi = w0i + dw;
            bool valid = (di >= 0) & (di < DD) & (hi >= 0) & (hi < HH)
                       & (wi >= 0) & (wi < WW);
            float wgt = fmul(fmul(dd ? fd : gd, dh ? fh : gh), dw ? fw : gw);
            wt[t] = valid ? wgt : 0.0f;
            int dc = min(max(di, 0), DD - 1);
            int hc = min(max(hi, 0), HH - 1);
            int wc = min(max(wi, 0), WW - 1);
            qa[t] = (dc * HH + hc) * WW + wc;
        }
        float acc = 0.0f;
        #pragma unroll
        for (int t = 0; t < 8; ++t) acc = fadd(acc, fmul(image[qa[t]], wt[t]));
        out[p] = acc;

        int di = (int)rintf(cd), hi = (int)rintf(ch), wi = (int)rintf(cw);
        bool valid = (di >= 0) & (di < DD) & (hi >= 0) & (hi < HH)
                   & (wi >= 0) & (wi < WW);
        int dc = min(max(di, 0), DD - 1);
        int hc = min(max(hi, 0), HH - 1);
        int wc = min(max(wi, 0), WW - 1);
        int q = (dc * HH + hc) * WW + wc;
        out[S + p]     = valid ? (float)cav[q] : 0.0f;
        out[2 * S + p] = valid ? (float)cor[q] : 0.0f;
    }
}

extern "C" void kernel_launch(void* const* d_in, const int* in_sizes, int n_in,
                              void* d_out, int out_size, void* d_ws, size_t ws_size,
                              hipStream_t stream) {
    const float* dvf0   = (const float*)d_in[0];
    const float* dvf1   = (const float*)d_in[1];
    const float* image  = (const float*)d_in[2];
    const int*   cav    = (const int*)d_in[3];
    const int*   cor    = (const int*)d_in[4];
    const float* w      = (const float*)d_in[5];

    float* out  = (float*)d_out;
    float* bufA = out;                    // ends as img, cav, cor
    float* bufB = out + (size_t)3 * S;    // ends as ddf5 (planar)
    float* bufC = (float*)d_ws;           // ddf4 scratch (if big enough)
    bool useWs = (d_ws != nullptr) && (ws_size >= (size_t)3 * S * sizeof(float));

    fused_init_s1<<<4000, 256, 0, stream>>>(dvf0, dvf1, w, bufB);     // ddf1
    warp_step<1><<<4000, 256, 0, stream>>>(bufB, bufA);               // ddf2
    warp_step<1><<<4000, 256, 0, stream>>>(bufA, bufB);               // ddf3
    if (useWs) {
        warp_step<2><<<4000, 256, 0, stream>>>(bufB, bufC);           // ddf4 -> ws
        final_phased<<<4000, 256, 0, stream>>>(bufC, image, cav, cor, bufA, bufB);
    } else {
        warp_step<2><<<4000, 256, 0, stream>>>(bufB, bufA);           // ddf4
        warp_flat<<<8000, 256, 0, stream>>>(bufA, bufB);              // ddf5
        final_kernel<<<8000, 256, 0, stream>>>(bufB, image, cav, cor, bufA);
    }
}

// Round 7
// 351.135 us; speedup vs baseline: 1.4506x; 1.0439x over previous
//
#include <hip/hip_runtime.h>

#define DD 160
#define HH 160
#define WW 160
#define PL (HH*WW)       // one z-plane = 25600 voxels
#define S (DD*PL)        // 4,096,000 voxels

__device__ __forceinline__ float fmul(float a, float b){ return __fmul_rn(a,b); }
__device__ __forceinline__ float fadd(float a, float b){ return __fadd_rn(a,b); }
__device__ __forceinline__ float fsub(float a, float b){ return __fsub_rn(a,b); }

// async global->LDS DMA, 16B per lane.  LDS dest is wave-uniform base + lane*16
// (matches our LINEAR chunk layout).  Global src is per-lane (clamped ok).
// Completion: __syncthreads() drains vmcnt.
__device__ __forceinline__ void dma16(const float* g, float* l) {
    __builtin_amdgcn_global_load_lds(
        (const __attribute__((address_space(1))) unsigned int*)g,
        (__attribute__((address_space(3))) unsigned int*)l,
        16, 0, 0);
}

// ---------------------------------------------------------------------------
// LDS tiles: 40-float (160B) rows spanning x in [x0-4, x0+36), 16B aligned.
// Halos sized for the TYPICAL displacement (sigma_k = 2^k/32); the per-voxel
// ok-check + exact global fallback handles tail violations bit-exactly.
//   fused_init_s1 : blend staged into LDS (reg path, H=1)      -> ddf1
//   warp_step<1>  : ddf2, ddf3, ddf4   (28.8 KB, 5 blk/CU, DMA-staged)
//   final_phased  : s5 via channel-phased H=2 LDS, double-buffered DMA
//                   (30.7 KB, 5 blk/CU) + image/label warp, one dispatch.
// ---------------------------------------------------------------------------

// out = in + trilinear_warp(in, in); planar in/out; LDS DMA-staged gather.
// Tile 32(x) x 8(y) x 4(z); grid 5*20*40 = 4000 blocks, XCD-swizzled.
template<int H>
__global__ __launch_bounds__(256) void warp_step(const float* __restrict__ in,
                                                 float* __restrict__ out) {
    constexpr int RZ = 4 + 2 * H;
    constexpr int RY = 8 + 2 * H;
    constexpr int ROWS = RZ * RY;
    constexpr int NCH4 = ROWS * 10;       // float4 chunks per channel
    constexpr int CHF  = ROWS * 40;       // floats per channel
    __shared__ __align__(16) float smem[3 * CHF];

    int b  = (blockIdx.x & 7) * 500 + (blockIdx.x >> 3);
    int ix = b % 5;
    int r  = b / 5;
    int iy = r % 20;
    int iz = r / 20;                 // 0..39
    int x0 = ix << 5, y0 = iy << 3, z0 = iz << 2;
    int xs4 = x0 - 4, ys = y0 - H, zs = z0 - H;

    int tid = threadIdx.x;
    for (int c = tid; c < NCH4; c += 256) {
        int row = c / 10;
        int col = (c - row * 10) << 2;
        int rz  = row / RY;
        int ry  = row - rz * RY;
        int cz = min(max(zs + rz, 0), DD - 1);
        int cy = min(max(ys + ry, 0), HH - 1);
        int q  = min(max((cz * HH + cy) * WW + xs4 + col, 0), S - 4);
        dma16(in + q,         smem + (c << 2));
        dma16(in + S + q,     smem + CHF + (c << 2));
        dma16(in + 2 * S + q, smem + 2 * CHF + (c << 2));
    }
    __syncthreads();

    int lane = tid & 63, wid = tid >> 6;
    int x = x0 | (lane & 31);
    int y = y0 | (wid << 1) | (lane >> 5);
    int lx = x - xs4;                 // 4..35
    int ly = y - ys;

    for (int j = 0; j < 4; ++j) {
        int z = z0 + j;
        int p = (z * HH + y) * WW + x;
        int lc = ((j + H) * RY + ly) * 40 + lx;
        float vd = smem[lc], vh = smem[CHF + lc], vw = smem[2 * CHF + lc];

        float cd = fadd((float)z, vd);
        float ch = fadd((float)y, vh);
        float cw = fadd((float)x, vw);

        float d0 = floorf(cd), h0 = floorf(ch), w0 = floorf(cw);
        float fd = fsub(cd, d0), fh = fsub(ch, h0), fw = fsub(cw, w0);
        float gd = fsub(1.0f, fd), gh = fsub(1.0f, fh), gw = fsub(1.0f, fw);
        int d0i = (int)d0, h0i = (int)h0, w0i = (int)w0;

        int rd = d0i - zs, rh = h0i - ys, rw = w0i - xs4;
        bool ok = ((unsigned)rd < (unsigned)(RZ - 1))
                & ((unsigned)rh < (unsigned)(RY - 1))
                & ((unsigned)rw < 39u);

        float r0, r1, r2;
        if (ok) {
            bool vA0 = (d0i >= 0), vA1 = (d0i + 1 < DD);
            bool vB0 = (h0i >= 0), vB1 = (h0i + 1 < HH);
            bool vC0 = (w0i >= 0), vC1 = (w0i + 1 < WW);
            float wt[8];
            #pragma unroll
            for (int t = 0; t < 8; ++t) {
                int dd = t >> 2, dh = (t >> 1) & 1, dw = t & 1;
                bool valid = (dd ? vA1 : vA0) & (dh ? vB1 : vB0) & (dw ? vC1 : vC0);
                float wgt = fmul(fmul(dd ? fd : gd, dh ? fh : gh), dw ? fw : gw);
                wt[t] = valid ? wgt : 0.0f;
            }
            int l0 = (rd * RY + rh) * 40 + rw;
            const int off[8] = { 0, 1, 40, 41,
                                 RY * 40, RY * 40 + 1, (RY + 1) * 40, (RY + 1) * 40 + 1 };
            float acc0 = 0.0f, acc1 = 0.0f, acc2 = 0.0f;
            #pragma unroll
            for (int t = 0; t < 8; ++t) {
                int li = l0 + off[t];
                acc0 = fadd(acc0, fmul(smem[li], wt[t]));
                acc1 = fadd(acc1, fmul(smem[CHF + li], wt[t]));
                acc2 = fadd(acc2, fmul(smem[2 * CHF + li], wt[t]));
            }
            r0 = fadd(vd, acc0);
            r1 = fadd(vh, acc1);
            r2 = fadd(vw, acc2);
        } else {
            int   qa[8];
            float wt[8];
            #pragma unroll
            for (int t = 0; t < 8; ++t) {
                int dd = t >> 2, dh = (t >> 1) & 1, dw = t & 1;
                int di = d0i + dd, hi = h0i + dh, wi = w0i + dw;
                bool valid = (di >= 0) & (di < DD) & (hi >= 0) & (hi < HH)
                           & (wi >= 0) & (wi < WW);
                float wgt = fmul(fmul(dd ? fd : gd, dh ? fh : gh), dw ? fw : gw);
                wt[t] = valid ? wgt : 0.0f;
                int dc = min(max(di, 0), DD - 1);
                int hc = min(max(hi, 0), HH - 1);
                int wc = min(max(wi, 0), WW - 1);
                qa[t] = (dc * HH + hc) * WW + wc;
            }
            float acc0 = 0.0f, acc1 = 0.0f, acc2 = 0.0f;
            #pragma unroll
            for (int t = 0; t < 8; ++t) {
                acc0 = fadd(acc0, fmul(in[qa[t]], wt[t]));
                acc1 = fadd(acc1, fmul(in[S + qa[t]], wt[t]));
                acc2 = fadd(acc2, fmul(in[2 * S + qa[t]], wt[t]));
            }
            r0 = fadd(vd, acc0);
            r1 = fadd(vh, acc1);
            r2 = fadd(vw, acc2);
        }

        out[p] = r0; out[S + p] = r1; out[2 * S + p] = r2;
    }
}

// init+s1 fused: blend((dvf0,dvf1),w)/32 staged into LDS via float4 regs.
__global__ __launch_bounds__(256) void fused_init_s1(const float* __restrict__ dvf0,
                                                     const float* __restrict__ dvf1,
                                                     const float* __restrict__ wp,
                                                     float* __restrict__ out) {
    constexpr int H = 1, RZ = 6, RY = 10, ROWS = 60, NCH4 = 600, CHF = 2400;
    __shared__ __align__(16) float smem[3 * CHF];
    float w = wp[0];
    float onew = fsub(1.0f, w);

    int b  = (blockIdx.x & 7) * 500 + (blockIdx.x >> 3);
    int ix = b % 5;
    int r  = b / 5;
    int iy = r % 20;
    int iz = r / 20;
    int x0 = ix << 5, y0 = iy << 3, z0 = iz << 2;
    int xs4 = x0 - 4, ys = y0 - H, zs = z0 - H;

    int tid = threadIdx.x;
    for (int c = tid; c < NCH4; c += 256) {
        int row = c / 10;
        int col = (c - row * 10) << 2;
        int rz  = row / RY;
        int ry  = row - rz * RY;
        int cz = min(max(zs + rz, 0), DD - 1);
        int cy = min(max(ys + ry, 0), HH - 1);
        int q  = min(max((cz * HH + cy) * WW + xs4 + col, 0), S - 4);
        #pragma unroll
        for (int ch = 0; ch < 3; ++ch) {
            float A[4], B[4], O[4];
            *(float4*)A = *(const float4*)(dvf0 + (size_t)ch * S + q);
            *(float4*)B = *(const float4*)(dvf1 + (size_t)ch * S + q);
            #pragma unroll
            for (int k = 0; k < 4; ++k)
                O[k] = fmul(fadd(fmul(A[k], onew), fmul(B[k], w)), 0.03125f);
            *(float4*)&smem[ch * CHF + row * 40 + col] = *(float4*)O;
        }
    }
    __syncthreads();

    int lane = tid & 63, wid = tid >> 6;
    int x = x0 | (lane & 31);
    int y = y0 | (wid << 1) | (lane >> 5);
    int lx = x - xs4;
    int ly = y - ys;

    for (int j = 0; j < 4; ++j) {
        int z = z0 + j;
        int p = (z * HH + y) * WW + x;
        int lc = ((j + H) * RY + ly) * 40 + lx;
        float vd = smem[lc], vh = smem[CHF + lc], vw = smem[2 * CHF + lc];

        float cd = fadd((float)z, vd);
        float ch = fadd((float)y, vh);
        float cw = fadd((float)x, vw);

        float d0 = floorf(cd), h0 = floorf(ch), w0 = floorf(cw);
        float fd = fsub(cd, d0), fh = fsub(ch, h0), fw = fsub(cw, w0);
        float gd = fsub(1.0f, fd), gh = fsub(1.0f, fh), gw = fsub(1.0f, fw);
        int d0i = (int)d0, h0i = (int)h0, w0i = (int)w0;

        int rd = d0i - zs, rh = h0i - ys, rw = w0i - xs4;
        bool ok = ((unsigned)rd < (unsigned)(RZ - 1))
                & ((unsigned)rh < (unsigned)(RY - 1))
                & ((unsigned)rw < 39u);

        float r0, r1, r2;
        if (ok) {
            bool vA0 = (d0i >= 0), vA1 = (d0i + 1 < DD);
            bool vB0 = (h0i >= 0), vB1 = (h0i + 1 < HH);
            bool vC0 = (w0i >= 0), vC1 = (w0i + 1 < WW);
            float wt[8];
            #pragma unroll
            for (int t = 0; t < 8; ++t) {
                int dd = t >> 2, dh = (t >> 1) & 1, dw = t & 1;
                bool valid = (dd ? vA1 : vA0) & (dh ? vB1 : vB0) & (dw ? vC1 : vC0);
                float wgt = fmul(fmul(dd ? fd : gd, dh ? fh : gh), dw ? fw : gw);
                wt[t] = valid ? wgt : 0.0f;
            }
            int l0 = (rd * RY + rh) * 40 + rw;
            const int off[8] = { 0, 1, 40, 41,
                                 RY * 40, RY * 40 + 1, (RY + 1) * 40, (RY + 1) * 40 + 1 };
            float acc0 = 0.0f, acc1 = 0.0f, acc2 = 0.0f;
            #pragma unroll
            for (int t = 0; t < 8; ++t) {
                int li = l0 + off[t];
                acc0 = fadd(acc0, fmul(smem[li], wt[t]));
                acc1 = fadd(acc1, fmul(smem[CHF + li], wt[t]));
                acc2 = fadd(acc2, fmul(smem[2 * CHF + li], wt[t]));
            }
            r0 = fadd(vd, acc0);
            r1 = fadd(vh, acc1);
            r2 = fadd(vw, acc2);
        } else {
            int   qa[8];
            float wt[8];
            #pragma unroll
            for (int t = 0; t < 8; ++t) {
                int dd = t >> 2, dh = (t >> 1) & 1, dw = t & 1;
                int di = d0i + dd, hi = h0i + dh, wi = w0i + dw;
                bool valid = (di >= 0) & (di < DD) & (hi >= 0) & (hi < HH)
                           & (wi >= 0) & (wi < WW);
                float wgt = fmul(fmul(dd ? fd : gd, dh ? fh : gh), dw ? fw : gw);
                wt[t] = valid ? wgt : 0.0f;
                int dc = min(max(di, 0), DD - 1);
                int hc = min(max(hi, 0), HH - 1);
                int wc = min(max(wi, 0), WW - 1);
                qa[t] = (dc * HH + hc) * WW + wc;
            }
            float acc0 = 0.0f, acc1 = 0.0f, acc2 = 0.0f;
            #pragma unroll
            for (int t = 0; t < 8; ++t) {
                float ga = fmul(fadd(fmul(dvf0[qa[t]], onew), fmul(dvf1[qa[t]], w)), 0.03125f);
                float gb = fmul(fadd(fmul(dvf0[S + qa[t]], onew), fmul(dvf1[S + qa[t]], w)), 0.03125f);
                float gc = fmul(fadd(fmul(dvf0[2 * S + qa[t]], onew), fmul(dvf1[2 * S + qa[t]], w)), 0.03125f);
                acc0 = fadd(acc0, fmul(ga, wt[t]));
                acc1 = fadd(acc1, fmul(gb, wt[t]));
                acc2 = fadd(acc2, fmul(gc, wt[t]));
            }
            r0 = fadd(vd, acc0);
            r1 = fadd(vh, acc1);
            r2 = fadd(vw, acc2);
        }

        out[p] = r0; out[S + p] = r1; out[2 * S + p] = r2;
    }
}

// s5 via channel-phased H=2 LDS, double-buffered DMA (30.7 KB, 5 blk/CU):
// prefetch phase c+1 under gather of phase c; then image/label warp.
__global__ __launch_bounds__(256) void final_phased(const float* __restrict__ ddf4,
                                                    const float* __restrict__ image,
                                                    const int* __restrict__ cav,
                                                    const int* __restrict__ cor,
                                                    float* __restrict__ outImg,
                                                    float* __restrict__ outDdf) {
    constexpr int RZ = 8, RY = 12, ROWS = 96, NCH4 = 960, CHF = 3840;
    __shared__ __align__(16) float smem[2 * CHF];   // 30.7 KB

    int b  = (blockIdx.x & 7) * 500 + (blockIdx.x >> 3);
    int ix = b % 5;
    int r  = b / 5;
    int iy = r % 20;
    int iz = r / 20;
    int x0 = ix << 5, y0 = iy << 3, z0 = iz << 2;
    int xs4 = x0 - 4, ys = y0 - 2, zs = z0 - 2;

    int tid = threadIdx.x;
    int lane = tid & 63, wid = tid >> 6;
    int x = x0 | (lane & 31);
    int y = y0 | (wid << 1) | (lane >> 5);
    int p0 = (z0 * HH + y) * WW + x;

    // ---- issue phase-0 staging DMA immediately
    #pragma unroll 1
    for (int cc = tid; cc < NCH4; cc += 256) {
        int row = cc / 10;
        int col = (cc - row * 10) << 2;
        int rz  = row / RY;
        int ry  = row - rz * RY;
        int cz = min(max(zs + rz, 0), DD - 1);
        int cy = min(max(ys + ry, 0), HH - 1);
        int q  = min(max((cz * HH + cy) * WW + xs4 + col, 0), S - 4);
        dma16(ddf4 + q, smem + (cc << 2));
    }

    // centers (coalesced)
    float ctd[4], cth[4], ctw[4];
    #pragma unroll
    for (int j = 0; j < 4; ++j) {
        ctd[j] = ddf4[p0 + j * PL];
        cth[j] = ddf4[S + p0 + j * PL];
        ctw[j] = ddf4[2 * S + p0 + j * PL];
    }

    // per-voxel precompute: weights + LDS base + ok mask
    float wt[4][8];
    int   l0[4];
    int   okm = 0;
    const int off[8] = { 0, 1, 40, 41,
                         RY * 40, RY * 40 + 1, (RY + 1) * 40, (RY + 1) * 40 + 1 };
    #pragma unroll
    for (int j = 0; j < 4; ++j) {
        int z = z0 + j;
        float cd = fadd((float)z, ctd[j]);
        float ch = fadd((float)y, cth[j]);
        float cw = fadd((float)x, ctw[j]);
        float d0 = floorf(cd), h0 = floorf(ch), w0 = floorf(cw);
        float fd = fsub(cd, d0), fh = fsub(ch, h0), fw = fsub(cw, w0);
        float gd = fsub(1.0f, fd), gh = fsub(1.0f, fh), gw = fsub(1.0f, fw);
        int d0i = (int)d0, h0i = (int)h0, w0i = (int)w0;

        bool vA0 = (d0i >= 0), vA1 = (d0i + 1 < DD);
        bool vB0 = (h0i >= 0), vB1 = (h0i + 1 < HH);
        bool vC0 = (w0i >= 0), vC1 = (w0i + 1 < WW);
        #pragma unroll
        for (int t = 0; t < 8; ++t) {
            int dd = t >> 2, dh = (t >> 1) & 1, dw = t & 1;
            bool valid = (dd ? vA1 : vA0) & (dh ? vB1 : vB0) & (dw ? vC1 : vC0);
            float wgt = fmul(fmul(dd ? fd : gd, dh ? fh : gh), dw ? fw : gw);
            wt[j][t] = valid ? wgt : 0.0f;
        }
        int rd = d0i - zs, rh = h0i - ys, rw = w0i - xs4;
        bool ok = ((unsigned)rd < (unsigned)(RZ - 1))
                & ((unsigned)rh < (unsigned)(RY - 1))
                & ((unsigned)rw < 39u);
        l0[j] = (rd * RY + rh) * 40 + rw;
        okm |= (ok ? 1 : 0) << j;
    }

    // rare fallback (halo bound violated): exact global gather, all channels
    float fb[3][4];
    if (okm != 15) {
        #pragma unroll
        for (int j = 0; j < 4; ++j) {
            if (!((okm >> j) & 1)) {
                int z = z0 + j;
                float cd = fadd((float)z, ctd[j]);
                float ch = fadd((float)y, cth[j]);
                float cw = fadd((float)x, ctw[j]);
                float d0 = floorf(cd), h0 = floorf(ch), w0 = floorf(cw);
                float fd = fsub(cd, d0), fh = fsub(ch, h0), fw = fsub(cw, w0);
                float gd = fsub(1.0f, fd), gh = fsub(1.0f, fh), gw = fsub(1.0f, fw);
                int d0i = (int)d0, h0i = (int)h0, w0i = (int)w0;
                int   qa[8];
                float wtf[8];
                #pragma unroll
                for (int t = 0; t < 8; ++t) {
                    int dd = t >> 2, dh = (t >> 1) & 1, dw = t & 1;
                    int di = d0i + dd, hi = h0i + dh, wi = w0i + dw;
                    bool valid = (di >= 0) & (di < DD) & (hi >= 0) & (hi < HH)
                               & (wi >= 0) & (wi < WW);
                    float wgt = fmul(fmul(dd ? fd : gd, dh ? fh : gh), dw ? fw : gw);
                    wtf[t] = valid ? wgt : 0.0f;
                    int dc = min(max(di, 0), DD - 1);
                    int hc = min(max(hi, 0), HH - 1);
                    int wc = min(max(wi, 0), WW - 1);
                    qa[t] = (dc * HH + hc) * WW + wc;
                }
                float a0 = 0.0f, a1 = 0.0f, a2 = 0.0f;
                #pragma unroll
                for (int t = 0; t < 8; ++t) {
                    a0 = fadd(a0, fmul(ddf4[qa[t]], wtf[t]));
                    a1 = fadd(a1, fmul(ddf4[S + qa[t]], wtf[t]));
                    a2 = fadd(a2, fmul(ddf4[2 * S + qa[t]], wtf[t]));
                }
                fb[0][j] = a0; fb[1][j] = a1; fb[2][j] = a2;
            }
        }
    }

    __syncthreads();   // phase-0 DMA complete

    // ---- three channel phases, double-buffered
    float rr[3][4];
    #pragma unroll
    for (int c = 0; c < 3; ++c) {
        if (c < 2) {
            const float* src = ddf4 + (size_t)(c + 1) * S;
            float* buf = smem + ((c + 1) & 1) * CHF;
            #pragma unroll 1
            for (int cc = tid; cc < NCH4; cc += 256) {
                int row = cc / 10;
                int col = (cc - row * 10) << 2;
                int rz  = row / RY;
                int ry  = row - rz * RY;
                int cz = min(max(zs + rz, 0), DD - 1);
                int cy = min(max(ys + ry, 0), HH - 1);
                int q  = min(max((cz * HH + cy) * WW + xs4 + col, 0), S - 4);
                dma16(src + q, buf + (cc << 2));
            }
        }
        const float* g = smem + (c & 1) * CHF;
        #pragma unroll
        for (int j = 0; j < 4; ++j) {
            float ctr = (c == 0) ? ctd[j] : (c == 1) ? cth[j] : ctw[j];
            float acc = 0.0f;
            if ((okm >> j) & 1) {
                #pragma unroll
                for (int t = 0; t < 8; ++t)
                    acc = fadd(acc, fmul(g[l0[j] + off[t]], wt[j][t]));
                rr[c][j] = fadd(ctr, acc);
            } else {
                rr[c][j] = fadd(ctr, fb[c][j]);
            }
            outDdf[(size_t)c * S + p0 + j * PL] = rr[c][j];
        }
        __syncthreads();   // drains DMA for c+1; everyone done reading buf c
    }

    // ---- image (trilinear) + labels (nearest) with ddf5
    #pragma unroll
    for (int j = 0; j < 4; ++j) {
        int z = z0 + j;
        int p = p0 + j * PL;
        float r0 = rr[0][j], r1 = rr[1][j], r2 = rr[2][j];

        float cd2 = fadd((float)z, r0);
        float ch2 = fadd((float)y, r1);
        float cw2 = fadd((float)x, r2);
        float d02 = floorf(cd2), h02 = floorf(ch2), w02 = floorf(cw2);
        float fd2 = fsub(cd2, d02), fh2 = fsub(ch2, h02), fw2 = fsub(cw2, w02);
        float gd2 = fsub(1.0f, fd2), gh2 = fsub(1.0f, fh2), gw2 = fsub(1.0f, fw2);
        int d2i = (int)d02, h2i = (int)h02, w2i = (int)w02;

        bool fast = ((unsigned)d2i < (unsigned)(DD - 1))
                  & ((unsigned)h2i < (unsigned)(HH - 1))
                  & ((unsigned)w2i < (unsigned)(WW - 1));
        if (fast) {
            const float* bp0 = image + (d2i * HH + h2i) * WW + w2i;
            const float* bp1 = bp0 + PL;
            float g[8];
            g[0] = bp0[0];      g[1] = bp0[1];
            g[2] = bp0[WW];     g[3] = bp0[WW + 1];
            g[4] = bp1[0];      g[5] = bp1[1];
            g[6] = bp1[WW];     g[7] = bp1[WW + 1];
            float w00 = fmul(gd2, gh2), w01 = fmul(gd2, fh2);
            float w10 = fmul(fd2, gh2), w11 = fmul(fd2, fh2);
            float wtf[8] = { fmul(w00, gw2), fmul(w00, fw2), fmul(w01, gw2), fmul(w01, fw2),
                             fmul(w10, gw2), fmul(w10, fw2), fmul(w11, gw2), fmul(w11, fw2) };
            float a = 0.0f;
            #pragma unroll
            for (int t = 0; t < 8; ++t) a = fadd(a, fmul(g[t], wtf[t]));
            outImg[p] = a;

            int di = (int)rintf(cd2), hi = (int)rintf(ch2), wi = (int)rintf(cw2);
            int q = (di * HH + hi) * WW + wi;
            outImg[S + p]     = (float)cav[q];
            outImg[2 * S + p] = (float)cor[q];
        } else {
            int   qb[8];
            float wtf[8];
            #pragma unroll
            for (int t = 0; t < 8; ++t) {
                int dd = t >> 2, dh = (t >> 1) & 1, dw = t & 1;
                int di = d2i + dd, hi = h2i + dh, wi = w2i + dw;
                bool valid = (di >= 0) & (di < DD) & (hi >= 0) & (hi < HH)
                           & (wi >= 0) & (wi < WW);
                float wgt = fmul(fmul(dd ? fd2 : gd2, dh ? fh2 : gh2), dw ? fw2 : gw2);
                wtf[t] = valid ? wgt : 0.0f;
                int dc = min(max(di, 0), DD - 1);
                int hc = min(max(hi, 0), HH - 1);
                int wc = min(max(wi, 0), WW - 1);
                qb[t] = (dc * HH + hc) * WW + wc;
            }
            float a = 0.0f;
            #pragma unroll
            for (int t = 0; t < 8; ++t) a = fadd(a, fmul(image[qb[t]], wtf[t]));
            outImg[p] = a;

            int di = (int)rintf(cd2), hi = (int)rintf(ch2), wi = (int)rintf(cw2);
            bool valid = (di >= 0) & (di < DD) & (hi >= 0) & (hi < HH)
                       & (wi >= 0) & (wi < WW);
            int dc = min(max(di, 0), DD - 1);
            int hc = min(max(hi, 0), HH - 1);
            int wc = min(max(wi, 0), WW - 1);
            int q = (dc * HH + hc) * WW + wc;
            outImg[S + p]     = valid ? (float)cav[q] : 0.0f;
            outImg[2 * S + p] = valid ? (float)cor[q] : 0.0f;
        }
    }
}

// ---- fallback path (d_ws too small): flat s5 + separate final.
__global__ __launch_bounds__(256) void warp_flat(const float* __restrict__ in,
                                                 float* __restrict__ out) {
    int b  = (blockIdx.x & 7) * 1000 + (blockIdx.x >> 3);
    int ix = b % 5;
    int r  = b / 5;
    int iy = r % 20;
    int iz = r / 20;
    int lane = threadIdx.x & 63, wid = threadIdx.x >> 6;
    int x  = (ix << 5) | (lane & 31);
    int y  = (iy << 3) | (wid << 1) | (lane >> 5);
    int z0 = iz << 1;
    int p0 = (z0 * HH + y) * WW + x;

    #pragma unroll
    for (int j = 0; j < 2; ++j) {
        int z = z0 + j;
        int p = p0 + j * PL;
        float vd = in[p], vh = in[S + p], vw = in[2 * S + p];
        float cd = fadd((float)z, vd);
        float ch = fadd((float)y, vh);
        float cw = fadd((float)x, vw);

        float d0 = floorf(cd), h0 = floorf(ch), w0 = floorf(cw);
        float fd = fsub(cd, d0), fh = fsub(ch, h0), fw = fsub(cw, w0);
        float gd = fsub(1.0f, fd), gh = fsub(1.0f, fh), gw = fsub(1.0f, fw);
        int d0i = (int)d0, h0i = (int)h0, w0i = (int)w0;

        int   qa[8];
        float wt[8];
        #pragma unroll
        for (int t = 0; t < 8; ++t) {
            int dd = t >> 2, dh = (t >> 1) & 1, dw = t & 1;
            int di = d0i + dd, hi = h0i + dh, wi = w0i + dw;
            bool valid = (di >= 0) & (di < DD) & (hi >= 0) & (hi < HH)
                       & (wi >= 0) & (wi < WW);
            float wgt = fmul(fmul(dd ? fd : gd, dh ? fh : gh), dw ? fw : gw);
            wt[t] = valid ? wgt : 0.0f;
            int dc = min(max(di, 0), DD - 1);
            int hc = min(max(hi, 0), HH - 1);
            int wc = min(max(wi, 0), WW - 1);
            qa[t] = (dc * HH + hc) * WW + wc;
        }
        float acc0 = 0.0f, acc1 = 0.0f, acc2 = 0.0f;
        #pragma unroll
        for (int t = 0; t < 8; ++t) {
            acc0 = fadd(acc0, fmul(in[qa[t]], wt[t]));
            acc1 = fadd(acc1, fmul(in[S + qa[t]], wt[t]));
            acc2 = fadd(acc2, fmul(in[2 * S + qa[t]], wt[t]));
        }
        out[p]         = fadd(vd, acc0);
        out[S + p]     = fadd(vh, acc1);
        out[2 * S + p] = fadd(vw, acc2);
    }
}

__global__ __launch_bounds__(256) void final_kernel(const float* __restrict__ ddf,
                                                    const float* __restrict__ image,
                                                    const int* __restrict__ cav,
                                                    const int* __restrict__ cor,
                                                    float* __restrict__ out) {
    int b  = (blockIdx.x & 7) * 1000 + (blockIdx.x >> 3);
    int ix = b % 5;
    int r  = b / 5;
    int iy = r % 20;
    int iz = r / 20;
    int lane = threadIdx.x & 63, wid = threadIdx.x >> 6;
    int x  = (ix << 5) | (lane & 31);
    int y  = (iy << 3) | (wid << 1) | (lane >> 5);
    int z0 = iz << 1;
    int p0 = (z0 * HH + y) * WW + x;

    #pragma unroll
    for (int j = 0; j < 2; ++j) {
        int z = z0 + j;
        int p = p0 + j * PL;
        float cd = fadd((float)z, ddf[p]);
        float ch = fadd((float)y, ddf[S + p]);
        float cw = fadd((float)x, ddf[2 * S + p]);

        float d0 = floorf(cd), h0 = floorf(ch), w0 = floorf(cw);
        float fd = fsub(cd, d0), fh = fsub(ch, h0), fw = fsub(cw, w0);
        float gd = fsub(1.0f, fd), gh = fsub(1.0f, fh), gw = fsub(1.0f, fw);
        int d0i = (int)d0, h0i = (int)h0, w0i = (int)w0;

        int   qa[8];
        float wt[8];
        #pragma unroll
        for (int t = 0; t < 8; ++t) {
            int dd = t >> 2, dh = (t >> 1) & 1, dw = t & 1;
            int di = d0i + dd, hi = h0i + dh, wi = w0i + dw;
            bool valid = (di >= 0) & (di < DD) & (hi >= 0) & (hi < HH)
                       & (wi >= 0) & (wi < WW);
            float wgt = fmul(fmul(dd ? fd : gd, dh ? fh : gh), dw ? fw : gw);
            wt[t] = valid ? wgt : 0.0f;
            int dc = min(max(di, 0), DD - 1);
            int hc = min(max(hi, 0), HH - 1);
            int wc = min(max(wi, 0), WW - 1);
            qa[t] = (dc * HH + hc) * WW + wc;
        }
        float acc = 0.0f;
        #pragma unroll
        for (int t = 0; t < 8; ++t) acc = fadd(acc, fmul(image[qa[t]], wt[t]));
        out[p] = acc;

        int di = (int)rintf(cd), hi = (int)rintf(ch), wi = (int)rintf(cw);
        bool valid = (di >= 0) & (di < DD) & (hi >= 0) & (hi < HH)
                   & (wi >= 0) & (wi < WW);
        int dc = min(max(di, 0), DD - 1);
        int hc = min(max(hi, 0), HH - 1);
        int wc = min(max(wi, 0), WW - 1);
        int q = (dc * HH + hc) * WW + wc;
        out[S + p]     = valid ? (float)cav[q] : 0.0f;
        out[2 * S + p] = valid ? (float)cor[q] : 0.0f;
    }
}

extern "C" void kernel_launch(void* const* d_in, const int* in_sizes, int n_in,
                              void* d_out, int out_size, void* d_ws, size_t ws_size,
                              hipStream_t stream) {
    const float* dvf0   = (const float*)d_in[0];
    const float* dvf1   = (const float*)d_in[1];
    const float* image  = (const float*)d_in[2];
    const int*   cav    = (const int*)d_in[3];
    const int*   cor    = (const int*)d_in[4];
    const float* w      = (const float*)d_in[5];

    float* out  = (float*)d_out;
    float* bufA = out;                    // ends as img, cav, cor
    float* bufB = out + (size_t)3 * S;    // ends as ddf5 (planar)
    float* bufC = (float*)d_ws;           // ddf4 scratch (if big enough)
    bool useWs = (d_ws != nullptr) && (ws_size >= (size_t)3 * S * sizeof(float));

    fused_init_s1<<<4000, 256, 0, stream>>>(dvf0, dvf1, w, bufB);     // ddf1
    warp_step<1><<<4000, 256, 0, stream>>>(bufB, bufA);               // ddf2
    warp_step<1><<<4000, 256, 0, stream>>>(bufA, bufB);               // ddf3
    if (useWs) {
        warp_step<1><<<4000, 256, 0, stream>>>(bufB, bufC);           // ddf4 -> ws
        final_phased<<<4000, 256, 0, stream>>>(bufC, image, cav, cor, bufA, bufB);
    } else {
        warp_step<1><<<4000, 256, 0, stream>>>(bufB, bufA);           // ddf4
        warp_flat<<<8000, 256, 0, stream>>>(bufA, bufB);              // ddf5
        final_kernel<<<8000, 256, 0, stream>>>(bufB, image, cav, cor, bufA);
    }
}